// Round 10
// baseline (425.844 us; speedup 1.0000x reference)
//
#include <hip/hip_runtime.h>
#include <math.h>

#define BB 8
#define CIN 12
#define LL 4096
#define DD 64
#define DIx 128
#define DSx 16
#define RR 10
#define KK 15
#define NCH 128     // scan chunks
#define CLEN 32     // LL/NCH
#define OUTL 40960  // LL*RR

typedef __attribute__((ext_vector_type(8))) short s8v;
typedef __attribute__((ext_vector_type(8))) __bf16 b8v;
typedef __attribute__((ext_vector_type(4))) float f4v;
union frag_u { s8v s; b8v b; };

__device__ __forceinline__ unsigned short f2b(float f) {
    unsigned int u = __float_as_uint(f);
    u = (u + 0x7fffu + ((u >> 16) & 1u)) >> 16;
    return (unsigned short)u;
}
__device__ __forceinline__ float b2f(unsigned short h) {
    return __uint_as_float(((unsigned int)h) << 16);
}

// ---------------------------------------------------------------
// Direct conv1d fp32 (conv_in, CI=12).
// ---------------------------------------------------------------
template<int CI, int CO, int COT, bool LEAKY>
__global__ __launch_bounds__(256) void k_conv(const float* __restrict__ in,
        const float* __restrict__ w, const float* __restrict__ bias,
        float* __restrict__ out) {
    const int LT = 1024;
    int tid = threadIdx.x;
    int bid = blockIdx.x;
    const int nlt = LL / LT;
    const int ncog = CO / COT;
    int lt = bid % nlt;
    int cog = (bid / nlt) % ncog;
    int b = bid / (nlt * ncog);
    int l0 = lt * LT + tid * 4;
    int co0 = cog * COT;

    float acc[COT][4];
#pragma unroll
    for (int c = 0; c < COT; ++c) {
        float bv = bias[co0 + c];
#pragma unroll
        for (int j = 0; j < 4; ++j) acc[c][j] = bv;
    }
    for (int ci = 0; ci < CI; ++ci) {
        const float* inp = in + ((size_t)b * CI + ci) * LL;
        float in20[20];
#pragma unroll
        for (int q = 0; q < 5; ++q) {
            int gi = l0 - 8 + q * 4;
            if (gi >= 0 && gi + 3 < LL) {
                float4 v = *(const float4*)(inp + gi);
                in20[q*4+0] = v.x; in20[q*4+1] = v.y;
                in20[q*4+2] = v.z; in20[q*4+3] = v.w;
            } else {
#pragma unroll
                for (int j = 0; j < 4; ++j) {
                    int g = gi + j;
                    in20[q*4+j] = (g >= 0 && g < LL) ? inp[g] : 0.f;
                }
            }
        }
#pragma unroll
        for (int c = 0; c < COT; ++c) {
            const float* wp = w + ((size_t)(co0 + c) * CI + ci) * KK;
#pragma unroll
            for (int k = 0; k < KK; ++k) {
                float wv = wp[k];
#pragma unroll
                for (int j = 0; j < 4; ++j)
                    acc[c][j] += wv * in20[j + k + 1];
            }
        }
    }
#pragma unroll
    for (int c = 0; c < COT; ++c) {
        float r[4];
#pragma unroll
        for (int j = 0; j < 4; ++j) {
            float v = acc[c][j];
            if (LEAKY) v = (v >= 0.f) ? v : 0.01f * v;
            r[j] = v;
        }
        *(float4*)(out + ((size_t)b * CO + co0 + c) * LL + l0) =
            make_float4(r[0], r[1], r[2], r[3]);
    }
}

// ---------------------------------------------------------------
// Weight prep: frag-linear bf16 for MFMA A-operand.
// ---------------------------------------------------------------
template<int CO_REAL, int NCOB>
__global__ __launch_bounds__(256) void k_wprep(const float* __restrict__ w,
        unsigned short* __restrict__ wp) {
    int idx = blockIdx.x * 256 + threadIdx.x;
    if (idx >= 15 * NCOB * 1024) return;
    int j = idx & 7;
    int lane = (idx >> 3) & 63;
    int cis = (idx >> 9) & 1;
    int rest = idx >> 10;
    int cob = rest % NCOB;
    int kk = rest / NCOB;
    int co = cob * 16 + (lane & 15);
    int ci = cis * 32 + ((lane >> 4) << 3) + j;
    float val = (co < CO_REAL) ? w[((size_t)co * 64 + ci) * KK + kk] : 0.f;
    wp[idx] = f2b(val);
}

// ---------------------------------------------------------------
// MFMA implicit-GEMM conv, K=15, CI=64, bf16 in.
// MODE 0: fp32 out + fused BN partial sums. MODE 1: bf16 out.
// ---------------------------------------------------------------
template<int CO_REAL, int NCOB, int MODE>
__global__ __launch_bounds__(256) void k_convmfma(
        const unsigned short* __restrict__ xt,
        const unsigned short* __restrict__ wp,
        const float* __restrict__ bias, void* __restrict__ outv,
        float* __restrict__ stats) {
    __shared__ unsigned short in_lds[142 * 72];
    const int NCOT = NCOB / 4;
    int tid = threadIdx.x;
    int bid = blockIdx.x;
    int lt = bid & 31;
    int cot = (bid >> 5) % NCOT;
    int b = bid / (32 * NCOT);
    int l0 = lt * 128;
#pragma unroll
    for (int i = 0; i < 5; ++i) {
        int q = i * 256 + tid;
        if (q < 1136) {
            int r = q >> 3, c8 = (q & 7) * 8;
            int gl = l0 - 7 + r;
            s8v v = {0,0,0,0,0,0,0,0};
            if (gl >= 0 && gl < LL)
                v = *(const s8v*)&xt[((size_t)b * LL + gl) * 64 + c8];
            *(s8v*)&in_lds[r * 72 + c8] = v;
        }
    }
    __syncthreads();
    int lane = tid & 63, wv = tid >> 6;
    int corow = (lane >> 4) << 2;
    f4v acc[4][2];
#pragma unroll
    for (int mt = 0; mt < 4; ++mt) {
#pragma unroll
        for (int r = 0; r < 4; ++r) {
            int co = cot * 64 + mt * 16 + corow + r;
            float bv = (co < CO_REAL) ? bias[co] : 0.f;
            acc[mt][0][r] = bv;
            acc[mt][1][r] = bv;
        }
    }
    int bcol = lane & 15;
    int cig = (lane >> 4) << 3;
    for (int k = 0; k < KK; ++k) {
#pragma unroll
        for (int cis = 0; cis < 2; ++cis) {
            frag_u a[4], bf[2];
#pragma unroll
            for (int mt = 0; mt < 4; ++mt)
                a[mt].s = *(const s8v*)&wp[((((k * NCOB + cot * 4 + mt) * 2 + cis) << 9)
                                           + (lane << 3))];
#pragma unroll
            for (int nt = 0; nt < 2; ++nt)
                bf[nt].s = *(const s8v*)&in_lds[(wv * 32 + nt * 16 + bcol + k) * 72
                                               + cis * 32 + cig];
#pragma unroll
            for (int mt = 0; mt < 4; ++mt)
#pragma unroll
                for (int nt = 0; nt < 2; ++nt)
                    acc[mt][nt] = __builtin_amdgcn_mfma_f32_16x16x32_bf16(
                        a[mt].b, bf[nt].b, acc[mt][nt], 0, 0, 0);
        }
    }
#pragma unroll
    for (int mt = 0; mt < 4; ++mt)
#pragma unroll
        for (int nt = 0; nt < 2; ++nt) {
            int l = l0 + wv * 32 + nt * 16 + bcol;
#pragma unroll
            for (int r = 0; r < 4; ++r) {
                int co = cot * 64 + mt * 16 + corow + r;
                if (co < CO_REAL) {
                    if (MODE == 0)
                        ((float*)outv)[((size_t)b * CO_REAL + co) * LL + l] = acc[mt][nt][r];
                    else
                        ((unsigned short*)outv)[((size_t)b * CO_REAL + co) * LL + l]
                            = f2b(acc[mt][nt][r]);
                }
            }
        }
    if (MODE == 0) {
#pragma unroll
        for (int mt = 0; mt < 4; ++mt)
#pragma unroll
            for (int r = 0; r < 4; ++r) {
                float sv = acc[mt][0][r] + acc[mt][1][r];
                float ssv = acc[mt][0][r]*acc[mt][0][r] + acc[mt][1][r]*acc[mt][1][r];
#pragma unroll
                for (int off = 1; off < 16; off <<= 1) {
                    sv  += __shfl_xor(sv, off);
                    ssv += __shfl_xor(ssv, off);
                }
                if (bcol == 0) {
                    int co = mt * 16 + corow + r;
                    atomicAdd(&stats[co], sv);
                    atomicAdd(&stats[64 + co], ssv);
                }
            }
    }
}

// ---------------------------------------------------------------
// in_proj GEMM: xz_bf16(32768,256) = A^T-view * W(256,64)^T
// ---------------------------------------------------------------
__global__ __launch_bounds__(256) void k_gemm_inproj(const float* __restrict__ A,
        const float* __restrict__ W, unsigned short* __restrict__ C) {
    __shared__ float At[64 * 132];
    __shared__ float Wt[64 * 132];
    int tid = threadIdx.x;
    int bid = blockIdx.x;
    int nb = bid & 1;
    int mb = bid >> 1;
    int row0 = mb * 128;
    int n0 = nb * 128;
    int b = row0 >> 12;
    int l0 = row0 & 4095;
#pragma unroll
    for (int it = 0; it < 8; ++it) {
        int idx = it * 256 + tid;
        int k = idx >> 5, m4 = (idx & 31) * 4;
        float4 v = *(const float4*)(A + ((size_t)b * DD + k) * LL + l0 + m4);
        *(float4*)&At[k * 132 + m4] = v;
    }
#pragma unroll
    for (int it = 0; it < 8; ++it) {
        int lin = it * 1024 + tid * 4;
        int n = lin >> 6, k = lin & 63;
        float4 v = *(const float4*)(W + (size_t)(n0 + n) * 64 + k);
        Wt[(k+0)*132 + n] = v.x; Wt[(k+1)*132 + n] = v.y;
        Wt[(k+2)*132 + n] = v.z; Wt[(k+3)*132 + n] = v.w;
    }
    __syncthreads();
    int tx = tid & 15, ty = tid >> 4;
    float acc[2][2][4][4] = {};
#pragma unroll 4
    for (int k = 0; k < 64; ++k) {
        float4 aLo = *(float4*)&At[k*132 + ty*4];
        float4 aHi = *(float4*)&At[k*132 + 64 + ty*4];
        float4 bLo = *(float4*)&Wt[k*132 + tx*4];
        float4 bHi = *(float4*)&Wt[k*132 + 64 + tx*4];
        float a0[4] = {aLo.x, aLo.y, aLo.z, aLo.w};
        float a1[4] = {aHi.x, aHi.y, aHi.z, aHi.w};
        float b0[4] = {bLo.x, bLo.y, bLo.z, bLo.w};
        float b1[4] = {bHi.x, bHi.y, bHi.z, bHi.w};
#pragma unroll
        for (int mm = 0; mm < 4; ++mm)
#pragma unroll
            for (int nn = 0; nn < 4; ++nn) {
                acc[0][0][mm][nn] += a0[mm] * b0[nn];
                acc[0][1][mm][nn] += a0[mm] * b1[nn];
                acc[1][0][mm][nn] += a1[mm] * b0[nn];
                acc[1][1][mm][nn] += a1[mm] * b1[nn];
            }
    }
#pragma unroll
    for (int qm = 0; qm < 2; ++qm)
#pragma unroll
        for (int mm = 0; mm < 4; ++mm) {
            int row = row0 + qm*64 + ty*4 + mm;
#pragma unroll
            for (int qn = 0; qn < 2; ++qn) {
                unsigned short o[4];
#pragma unroll
                for (int nn = 0; nn < 4; ++nn) o[nn] = f2b(acc[qm][qn][mm][nn]);
                *(uint2*)&C[(size_t)row * 256 + n0 + qn*64 + tx*4] = *(uint2*)o;
            }
        }
}

// ---------------------------------------------------------------
// x_proj GEMM with FUSED depthwise conv+silu.
// ---------------------------------------------------------------
template<int NW>
__global__ __launch_bounds__(256) void k_gemm64dw(
        const unsigned short* __restrict__ xzb,
        const float* __restrict__ dww, const float* __restrict__ dwb,
        const float* __restrict__ W, float* __restrict__ out) {
    __shared__ float At[64 * 132];
    __shared__ float Wt[64 * 68];
    __shared__ float sdw[128][4];
    __shared__ float sbias[128];
    int tid = threadIdx.x;
    int row0 = blockIdx.x * 128;
    int l0 = row0 & 4095;
    if (tid < 128) {
        *(float4*)&sdw[tid][0] = *(const float4*)(dww + tid * 4);
        sbias[tid] = dwb[tid];
    }
    int tx = tid & 15, ty = tid >> 4;
    float acc[2][4][4] = {};
#pragma unroll
    for (int kt = 0; kt < 2; ++kt) {
        __syncthreads();
#pragma unroll
        for (int it = 0; it < 4; ++it) {
            int task = it * 256 + tid;
            int m = task >> 3;
            int k8 = (task & 7) * 8;
            int d0 = kt * 64 + k8;
            float s[8];
#pragma unroll
            for (int j = 0; j < 8; ++j) s[j] = sbias[d0 + j];
#pragma unroll
            for (int tap = 0; tap < 4; ++tap) {
                if (l0 + m - 3 + tap >= 0) {
                    s8v xv = *(const s8v*)&xzb[(size_t)(row0 + m - 3 + tap) * 256 + d0];
#pragma unroll
                    for (int j = 0; j < 8; ++j)
                        s[j] += b2f((unsigned short)xv[j]) * sdw[d0 + j][tap];
                }
            }
#pragma unroll
            for (int j = 0; j < 8; ++j) {
                float v = s[j];
                At[(k8 + j) * 132 + m] = v / (1.f + __expf(-v));
            }
        }
#pragma unroll
        for (int it = 0; it < 4; ++it) {
            int lin = it * 1024 + tid * 4;
            int n = lin >> 6, k = lin & 63;
            float4 v = make_float4(0.f, 0.f, 0.f, 0.f);
            if (n < NW)
                v = *(const float4*)(W + (size_t)n * 128 + kt*64 + k);
            Wt[(k+0)*68 + n] = v.x; Wt[(k+1)*68 + n] = v.y;
            Wt[(k+2)*68 + n] = v.z; Wt[(k+3)*68 + n] = v.w;
        }
        __syncthreads();
#pragma unroll 4
        for (int k = 0; k < 64; ++k) {
            float4 aLo = *(float4*)&At[k*132 + ty*4];
            float4 aHi = *(float4*)&At[k*132 + 64 + ty*4];
            float4 b4  = *(float4*)&Wt[k*68 + tx*4];
            float a0[4] = {aLo.x, aLo.y, aLo.z, aLo.w};
            float a1[4] = {aHi.x, aHi.y, aHi.z, aHi.w};
            float bv[4] = {b4.x, b4.y, b4.z, b4.w};
#pragma unroll
            for (int mm = 0; mm < 4; ++mm)
#pragma unroll
                for (int nn = 0; nn < 4; ++nn) {
                    acc[0][mm][nn] += a0[mm] * bv[nn];
                    acc[1][mm][nn] += a1[mm] * bv[nn];
                }
        }
    }
#pragma unroll
    for (int qm = 0; qm < 2; ++qm)
#pragma unroll
        for (int mm = 0; mm < 4; ++mm) {
            int row = row0 + qm*64 + ty*4 + mm;
            *(float4*)(out + (size_t)row * 64 + tx*4) =
                make_float4(acc[qm][mm][0], acc[qm][mm][1],
                            acc[qm][mm][2], acc[qm][mm][3]);
        }
}

// ---------------------------------------------------------------
// out_proj GEMM (A = ym bf16) + residual + bf16 transposed write.
// ---------------------------------------------------------------
__global__ __launch_bounds__(256) void k_gemm64_tr(
        const unsigned short* __restrict__ A, const float* __restrict__ W,
        const float* __restrict__ res, unsigned short* __restrict__ out) {
    __shared__ float smem[13312];
    float* At = smem;
    float* Wt = smem + 64*132;
    int tid = threadIdx.x;
    int row0 = blockIdx.x * 128;
    int tx = tid & 15, ty = tid >> 4;
    int b = row0 >> 12, l0 = row0 & 4095;
    float acc[2][4][4] = {};
#pragma unroll
    for (int kt = 0; kt < 2; ++kt) {
        __syncthreads();
#pragma unroll
        for (int it = 0; it < 4; ++it) {
            int task = it * 256 + tid;
            int m = task >> 3;
            int k8 = (task & 7) * 8;
            s8v v = *(const s8v*)&A[(size_t)(row0 + m) * 128 + kt*64 + k8];
#pragma unroll
            for (int j = 0; j < 8; ++j)
                At[(k8 + j) * 132 + m] = b2f((unsigned short)v[j]);
        }
#pragma unroll
        for (int it = 0; it < 4; ++it) {
            int lin = it * 1024 + tid * 4;
            int n = lin >> 6, k = lin & 63;
            float4 v = *(const float4*)(W + (size_t)n * 128 + kt*64 + k);
            Wt[(k+0)*68 + n] = v.x; Wt[(k+1)*68 + n] = v.y;
            Wt[(k+2)*68 + n] = v.z; Wt[(k+3)*68 + n] = v.w;
        }
        __syncthreads();
#pragma unroll 4
        for (int k = 0; k < 64; ++k) {
            float4 aLo = *(float4*)&At[k*132 + ty*4];
            float4 aHi = *(float4*)&At[k*132 + 64 + ty*4];
            float4 b4  = *(float4*)&Wt[k*68 + tx*4];
            float a0[4] = {aLo.x, aLo.y, aLo.z, aLo.w};
            float a1[4] = {aHi.x, aHi.y, aHi.z, aHi.w};
            float bv[4] = {b4.x, b4.y, b4.z, b4.w};
#pragma unroll
            for (int mm = 0; mm < 4; ++mm)
#pragma unroll
                for (int nn = 0; nn < 4; ++nn) {
                    acc[0][mm][nn] += a0[mm] * bv[nn];
                    acc[1][mm][nn] += a1[mm] * bv[nn];
                }
        }
    }
    __syncthreads();
    float* tile = smem;                               // [128][68]
    unsigned short* resb = (unsigned short*)(smem + 8704);  // [128][72]
#pragma unroll
    for (int qm = 0; qm < 2; ++qm)
#pragma unroll
        for (int mm = 0; mm < 4; ++mm) {
            int lrow = qm*64 + ty*4 + mm;
            *(float4*)&tile[lrow*68 + tx*4] = make_float4(
                acc[qm][mm][0], acc[qm][mm][1], acc[qm][mm][2], acc[qm][mm][3]);
        }
#pragma unroll
    for (int it = 0; it < 8; ++it) {
        int idx = it * 256 + tid;
        int d = idx >> 5, l4 = (idx & 31) * 4;
        float4 rv = *(const float4*)(res + ((size_t)b * DD + d) * LL + l0 + l4);
        resb[(l4+0)*72 + d] = f2b(rv.x);
        resb[(l4+1)*72 + d] = f2b(rv.y);
        resb[(l4+2)*72 + d] = f2b(rv.z);
        resb[(l4+3)*72 + d] = f2b(rv.w);
    }
    __syncthreads();
#pragma unroll
    for (int it = 0; it < 4; ++it) {
        int idx = it * 256 + tid;
        int l = idx >> 3, c8 = (idx & 7) * 8;
        unsigned short o[8];
#pragma unroll
        for (int j = 0; j < 8; ++j)
            o[j] = f2b(tile[l*68 + c8 + j] + b2f(resb[l*72 + c8 + j]));
        *(s8v*)&out[((size_t)b * LL + l0 + l) * 64 + c8] = *(s8v*)o;
    }
}

// ---------------------------------------------------------------
// Scan phase 1: thread owns d; dwconv+silu + dt_proj fused.
// ---------------------------------------------------------------
__global__ __launch_bounds__(256) void k_scan1(
        const unsigned short* __restrict__ xzb, const float* __restrict__ dbl,
        const float* __restrict__ dww, const float* __restrict__ dwb,
        const float* __restrict__ dtw, const float* __restrict__ dtbias,
        const float* __restrict__ A_log, float* __restrict__ P,
        float* __restrict__ Q) {
    __shared__ float sdbl[2][CLEN][64];
    int tid = threadIdx.x;
    int bid = blockIdx.x;
    int b = bid >> 6;
    int cpair = bid & 63;
    int half = tid >> 7;
    int d = tid & 127;
    int c = cpair * 2 + half;
    {
        const float4* src = (const float4*)(dbl +
            ((size_t)b * LL + (size_t)cpair * 2 * CLEN) * 64);
        float4* dst = (float4*)&sdbl[0][0][0];
#pragma unroll
        for (int i = 0; i < 4; ++i) dst[i * 256 + tid] = src[i * 256 + tid];
    }
    __syncthreads();
    float4 w4 = *(const float4*)(dtw + d * 4);
    float dbias = dtbias[d];
    float4 cw = *(const float4*)(dww + d * 4);
    float cbias = dwb[d];
    float Ads[16], h[16], p[16];
#pragma unroll
    for (int s = 0; s < 16; ++s) {
        Ads[s] = -__expf(A_log[d * DSx + s]);
        h[s] = 0.f; p[s] = 1.f;
    }
    int l0 = c * CLEN;
    const unsigned short* px = xzb + ((size_t)b * LL + l0) * 256 + d;
    float w0 = 0.f, w1 = 0.f, w2 = 0.f;
    if (l0) { w0 = b2f(px[-768]); w1 = b2f(px[-512]); w2 = b2f(px[-256]); }
    for (int t = 0; t < CLEN; ++t) {
        float cur = b2f(px[(size_t)t * 256]);
        float sv = cbias + w0*cw.x + w1*cw.y + w2*cw.z + cur*cw.w;
        float xs = sv / (1.f + __expf(-sv));
        w0 = w1; w1 = w2; w2 = cur;
        float4 di = *(const float4*)&sdbl[half][t][0];
        float dtv = di.x*w4.x + di.y*w4.y + di.z*w4.z + di.w*w4.w + dbias;
        dtv = (dtv > 15.f) ? dtv : log1pf(__expf(dtv));
        float dx = dtv * xs;
#pragma unroll
        for (int s = 0; s < 16; ++s) {
            float da = __expf(dtv * Ads[s]);
            h[s] = da * h[s] + dx * sdbl[half][t][4 + s];
            p[s] *= da;
        }
    }
    float* Pp = P + (size_t)c * 16384 + (size_t)(b * 128 + d) * 16;
    float* Qp = Q + (size_t)c * 16384 + (size_t)(b * 128 + d) * 16;
#pragma unroll
    for (int s4 = 0; s4 < 4; ++s4) {
        *(float4*)(Pp + s4*4) = make_float4(p[s4*4], p[s4*4+1], p[s4*4+2], p[s4*4+3]);
        *(float4*)(Qp + s4*4) = make_float4(h[s4*4], h[s4*4+1], h[s4*4+2], h[s4*4+3]);
    }
}

// ---------------------------------------------------------------
// Scan phase 2: prefix over chunks + zero BN stats accum.
// ---------------------------------------------------------------
__global__ __launch_bounds__(256) void k_scan2(const float* __restrict__ P,
        const float* __restrict__ Q, float* __restrict__ Hin,
        float* __restrict__ stats) {
    int chain = blockIdx.x * 256 + threadIdx.x;  // 16384
    if (blockIdx.x == 0 && threadIdx.x < 128) stats[threadIdx.x] = 0.f;
    float carry = 0.f;
    for (int c = 0; c < NCH; ++c) {
        Hin[(size_t)c * 16384 + chain] = carry;
        carry = P[(size_t)c * 16384 + chain] * carry + Q[(size_t)c * 16384 + chain];
    }
}

// ---------------------------------------------------------------
// Scan phase 3: thread owns d; fused dwconv + dt + gate; ym bf16 out.
// ---------------------------------------------------------------
__global__ __launch_bounds__(256) void k_scan3(
        const unsigned short* __restrict__ xzb, const float* __restrict__ dbl,
        const float* __restrict__ dww, const float* __restrict__ dwb,
        const float* __restrict__ dtw, const float* __restrict__ dtbias,
        const float* __restrict__ A_log, const float* __restrict__ Hin,
        const float* __restrict__ Dssm, unsigned short* __restrict__ ymb) {
    __shared__ float sdbl[2][CLEN][64];
    int tid = threadIdx.x;
    int bid = blockIdx.x;
    int b = bid >> 6;
    int cpair = bid & 63;
    int half = tid >> 7;
    int d = tid & 127;
    int c = cpair * 2 + half;
    {
        const float4* src = (const float4*)(dbl +
            ((size_t)b * LL + (size_t)cpair * 2 * CLEN) * 64);
        float4* dst = (float4*)&sdbl[0][0][0];
#pragma unroll
        for (int i = 0; i < 4; ++i) dst[i * 256 + tid] = src[i * 256 + tid];
    }
    __syncthreads();
    float4 w4 = *(const float4*)(dtw + d * 4);
    float dbias = dtbias[d];
    float4 cw = *(const float4*)(dww + d * 4);
    float cbias = dwb[d];
    float Dv = Dssm[d];
    float Ads[16], h[16];
#pragma unroll
    for (int s = 0; s < 16; ++s)
        Ads[s] = -__expf(A_log[d * DSx + s]);
    const float* Hp = Hin + (size_t)c * 16384 + (size_t)(b * 128 + d) * 16;
#pragma unroll
    for (int s4 = 0; s4 < 4; ++s4) {
        float4 hv = *(const float4*)(Hp + s4*4);
        h[s4*4+0] = hv.x; h[s4*4+1] = hv.y; h[s4*4+2] = hv.z; h[s4*4+3] = hv.w;
    }
    int l0 = c * CLEN;
    size_t rowbase = (size_t)b * LL + l0;
    const unsigned short* px = xzb + rowbase * 256 + d;
    const unsigned short* pz = xzb + rowbase * 256 + 128 + d;
    unsigned short* pym = ymb + rowbase * 128 + d;
    float w0 = 0.f, w1 = 0.f, w2 = 0.f;
    if (l0) { w0 = b2f(px[-768]); w1 = b2f(px[-512]); w2 = b2f(px[-256]); }
    for (int t = 0; t < CLEN; ++t) {
        float cur = b2f(px[(size_t)t * 256]);
        float sv = cbias + w0*cw.x + w1*cw.y + w2*cw.z + cur*cw.w;
        float xs = sv / (1.f + __expf(-sv));
        w0 = w1; w1 = w2; w2 = cur;
        float4 di = *(const float4*)&sdbl[half][t][0];
        float dtv = di.x*w4.x + di.y*w4.y + di.z*w4.z + di.w*w4.w + dbias;
        dtv = (dtv > 15.f) ? dtv : log1pf(__expf(dtv));
        float dx = dtv * xs;
        float y0 = 0.f, y1 = 0.f;
#pragma unroll
        for (int s = 0; s < 8; ++s) {
            float da = __expf(dtv * Ads[s]);
            h[s] = da * h[s] + dx * sdbl[half][t][4 + s];
            y0 += h[s] * sdbl[half][t][20 + s];
        }
#pragma unroll
        for (int s = 8; s < 16; ++s) {
            float da = __expf(dtv * Ads[s]);
            h[s] = da * h[s] + dx * sdbl[half][t][4 + s];
            y1 += h[s] * sdbl[half][t][20 + s];
        }
        float y = y0 + y1 + xs * Dv;
        float zv = b2f(pz[(size_t)t * 256]);
        y *= zv / (1.f + __expf(-zv));
        pym[(size_t)t * 128] = f2b(y);
    }
}

// ---------------------------------------------------------------
// BN apply + residual + transpose -> bf16 (B,L,64).
// ---------------------------------------------------------------
__global__ __launch_bounds__(256) void k_bnapply_t(const float* __restrict__ xm,
        const float* __restrict__ stats, const float* __restrict__ gamma,
        const float* __restrict__ beta, const float* __restrict__ xin,
        unsigned short* __restrict__ xf) {
    __shared__ float t[64][65];
    int tid = threadIdx.x;
    int b = blockIdx.x >> 6;
    int l0 = (blockIdx.x & 63) * 64;
    const float inv = 1.f / (float)(BB * LL);
#pragma unroll
    for (int it = 0; it < 16; ++it) {
        int idx = it * 256 + tid;
        int c = idx >> 6, l = idx & 63;
        float mean = stats[c] * inv;
        float var  = stats[64 + c] * inv - mean * mean;
        float g = gamma[c] * rsqrtf(var + 1e-5f);
        float sh = beta[c] - mean * g;
        size_t addr = ((size_t)b * DD + c) * LL + l0 + l;
        t[c][l] = xm[addr] * g + sh + xin[addr];
    }
    __syncthreads();
#pragma unroll
    for (int it = 0; it < 2; ++it) {
        int idx = it * 256 + tid;
        int l = idx >> 3, c8 = (idx & 7) * 8;
        unsigned short o[8];
#pragma unroll
        for (int j = 0; j < 8; ++j) o[j] = f2b(t[c8 + j][l]);
        *(s8v*)&xf[((size_t)b * LL + l0 + l) * 64 + c8] = *(s8v*)o;
    }
}

// ---------------------------------------------------------------
// PixelShuffle(r=10) + linear upsample + add (xp bf16 in).
// ---------------------------------------------------------------
__global__ __launch_bounds__(256) void k_final(const unsigned short* __restrict__ xp,
        const float* __restrict__ x, float* __restrict__ out) {
    __shared__ float xps[10][257];
    __shared__ float xr[258];
    int tid = threadIdx.x;
    int bid = blockIdx.x;
    int lt = bid & 15;
    int c = (bid >> 4) % 12;
    int b = bid / (16 * 12);
    int l0 = lt * 256;
#pragma unroll
    for (int r = 0; r < 10; ++r)
        xps[r][tid] = b2f(xp[((size_t)b * 120 + r * 12 + c) * LL + l0 + tid]);
    const float* xrow = x + ((size_t)b * 12 + c) * LL;
    for (int i = tid; i < 258; i += 256) {
        int g = l0 - 1 + i;
        g = (g < 0) ? 0 : ((g > LL - 1) ? LL - 1 : g);
        xr[i] = xrow[g];
    }
    __syncthreads();
    size_t obase = ((size_t)b * 12 + c) * OUTL + (size_t)l0 * 10;
#pragma unroll
    for (int u = 0; u < 10; ++u) {
        int j = u * 256 + tid;
        int jg = l0 * 10 + j;
        int l = j / 10, r = j - l * 10;
        float ps = xps[r][l];
        float src = ((float)jg + 0.5f) * 0.1f - 0.5f;
        src = fmaxf(src, 0.f);
        int i0 = (int)src;
        if (i0 > LL - 1) i0 = LL - 1;
        int i1 = (i0 + 1 < LL) ? i0 + 1 : LL - 1;
        float frac = src - (float)i0;
        float up = xr[i0 - l0 + 1] * (1.f - frac) + xr[i1 - l0 + 1] * frac;
        out[obase + j] = ps + up;
    }
}

// ---------------------------------------------------------------
extern "C" void kernel_launch(void* const* d_in, const int* in_sizes, int n_in,
                              void* d_out, int out_size, void* d_ws, size_t ws_size,
                              hipStream_t stream) {
    const float* x          = (const float*)d_in[0];
    const float* conv_in_w  = (const float*)d_in[1];
    const float* conv_in_b  = (const float*)d_in[2];
    const float* in_proj_w  = (const float*)d_in[3];
    const float* dw_w       = (const float*)d_in[4];
    const float* dw_b       = (const float*)d_in[5];
    const float* x_proj_w   = (const float*)d_in[6];
    const float* dt_w       = (const float*)d_in[7];
    const float* dt_b       = (const float*)d_in[8];
    const float* A_log      = (const float*)d_in[9];
    const float* Dssm       = (const float*)d_in[10];
    const float* out_proj_w = (const float*)d_in[11];
    const float* cm_w       = (const float*)d_in[12];
    const float* cm_b       = (const float*)d_in[13];
    const float* bn_g       = (const float*)d_in[14];
    const float* bn_be      = (const float*)d_in[15];
    const float* ps_w       = (const float*)d_in[16];
    const float* ps_b       = (const float*)d_in[17];

    // Workspace layout (float offsets, NO overlaps):
    //  xin_bdl  [0          , 2,097,152)   B*64*L fp32
    //  xzb      [2,097,152  , 6,291,456)   32768*256 bf16 (4,194,304 float-slots)
    //  dbl64    [6,291,456  , 8,388,608)   32768*64 fp32
    //  P        [8,388,608  , 10,485,760)  NCH*16384 fp32
    //  Q        [10,485,760 , 12,582,912)
    //  Hin      [12,582,912 , 14,680,064)
    //  stats    [14,680,064 , 14,680,192)  128 fp32
    //  ymb      [14,680,192 , 16,777,344)  32768*128 bf16 (2,097,152 slots)
    //  xmt      [16,777,344 , 17,825,920)  32768*64 bf16 (1,048,576 slots)
    //  xmerge   [17,825,920 , 19,923,072)  B*64*L fp32
    //  xf       [19,923,072 , 20,971,648)  32768*64 bf16
    //  wp_ps    [20,971,648 , 21,033,088)  122,880 bf16
    //  wp_mg    [21,033,088 , 21,063,808)  61,440 bf16
    //  xpb      [21,063,808 , 23,029,888)  B*120*L bf16 (1,966,080 slots)
    float* ws = (float*)d_ws;
    float* xin_bdl = ws;
    unsigned short* xzb = (unsigned short*)(ws + 2097152);
    float* dbl64   = ws + 6291456;
    float* P       = ws + 8388608;
    float* Q       = ws + 10485760;
    float* Hin     = ws + 12582912;
    float* stats   = ws + 14680064;
    unsigned short* ymb = (unsigned short*)(ws + 14680192);
    unsigned short* xmt = (unsigned short*)(ws + 16777344);
    float* xmerge  = ws + 17825920;
    unsigned short* xf  = (unsigned short*)(ws + 19923072);
    unsigned short* wp_ps = (unsigned short*)(ws + 20971648);
    unsigned short* wp_mg = (unsigned short*)(ws + 21033088);
    unsigned short* xpb = (unsigned short*)(ws + 21063808);

    k_conv<CIN, 64, 2, true><<<1024, 256, 0, stream>>>(x, conv_in_w, conv_in_b, xin_bdl);
    k_gemm_inproj<<<512, 256, 0, stream>>>(xin_bdl, in_proj_w, xzb);
    k_gemm64dw<36><<<256, 256, 0, stream>>>(xzb, dw_w, dw_b, x_proj_w, dbl64);
    k_scan1<<<512, 256, 0, stream>>>(xzb, dbl64, dw_w, dw_b, dt_w, dt_b, A_log, P, Q);
    k_scan2<<<64, 256, 0, stream>>>(P, Q, Hin, stats);
    k_scan3<<<512, 256, 0, stream>>>(xzb, dbl64, dw_w, dw_b, dt_w, dt_b, A_log, Hin,
                                     Dssm, ymb);
    k_wprep<120, 8><<<480, 256, 0, stream>>>(ps_w, wp_ps);
    k_wprep<64, 4><<<240, 256, 0, stream>>>(cm_w, wp_mg);
    k_gemm64_tr<<<256, 256, 0, stream>>>(ymb, out_proj_w, xin_bdl, xmt);
    k_convmfma<64, 4, 0><<<256, 256, 0, stream>>>(xmt, wp_mg, cm_b, xmerge, stats);
    k_bnapply_t<<<512, 256, 0, stream>>>(xmerge, stats, bn_g, bn_be, xin_bdl, xf);
    k_convmfma<120, 8, 1><<<512, 256, 0, stream>>>(xf, wp_ps, ps_b, xpb, nullptr);
    k_final<<<1536, 256, 0, stream>>>(xpb, x, (float*)d_out);
}

// Round 11
// 318.591 us; speedup vs baseline: 1.3366x; 1.3366x over previous
//
#include <hip/hip_runtime.h>
#include <math.h>

#define BB 8
#define CIN 12
#define LL 4096
#define DD 64
#define DIx 128
#define DSx 16
#define RR 10
#define KK 15
#define NCH 128     // scan chunks
#define CLEN 32     // LL/NCH
#define OUTL 40960  // LL*RR

typedef __attribute__((ext_vector_type(8))) short s8v;
typedef __attribute__((ext_vector_type(8))) __bf16 b8v;
typedef __attribute__((ext_vector_type(4))) float f4v;
union frag_u { s8v s; b8v b; };

__device__ __forceinline__ unsigned short f2b(float f) {
    unsigned int u = __float_as_uint(f);
    u = (u + 0x7fffu + ((u >> 16) & 1u)) >> 16;
    return (unsigned short)u;
}
__device__ __forceinline__ float b2f(unsigned short h) {
    return __uint_as_float(((unsigned int)h) << 16);
}

// ---------------------------------------------------------------
// Direct conv1d fp32 (conv_in, CI=12).
// ---------------------------------------------------------------
template<int CI, int CO, int COT, bool LEAKY>
__global__ __launch_bounds__(256) void k_conv(const float* __restrict__ in,
        const float* __restrict__ w, const float* __restrict__ bias,
        float* __restrict__ out) {
    const int LT = 1024;
    int tid = threadIdx.x;
    int bid = blockIdx.x;
    const int nlt = LL / LT;
    const int ncog = CO / COT;
    int lt = bid % nlt;
    int cog = (bid / nlt) % ncog;
    int b = bid / (nlt * ncog);
    int l0 = lt * LT + tid * 4;
    int co0 = cog * COT;

    float acc[COT][4];
#pragma unroll
    for (int c = 0; c < COT; ++c) {
        float bv = bias[co0 + c];
#pragma unroll
        for (int j = 0; j < 4; ++j) acc[c][j] = bv;
    }
    for (int ci = 0; ci < CI; ++ci) {
        const float* inp = in + ((size_t)b * CI + ci) * LL;
        float in20[20];
#pragma unroll
        for (int q = 0; q < 5; ++q) {
            int gi = l0 - 8 + q * 4;
            if (gi >= 0 && gi + 3 < LL) {
                float4 v = *(const float4*)(inp + gi);
                in20[q*4+0] = v.x; in20[q*4+1] = v.y;
                in20[q*4+2] = v.z; in20[q*4+3] = v.w;
            } else {
#pragma unroll
                for (int j = 0; j < 4; ++j) {
                    int g = gi + j;
                    in20[q*4+j] = (g >= 0 && g < LL) ? inp[g] : 0.f;
                }
            }
        }
#pragma unroll
        for (int c = 0; c < COT; ++c) {
            const float* wp = w + ((size_t)(co0 + c) * CI + ci) * KK;
#pragma unroll
            for (int k = 0; k < KK; ++k) {
                float wv = wp[k];
#pragma unroll
                for (int j = 0; j < 4; ++j)
                    acc[c][j] += wv * in20[j + k + 1];
            }
        }
    }
#pragma unroll
    for (int c = 0; c < COT; ++c) {
        float r[4];
#pragma unroll
        for (int j = 0; j < 4; ++j) {
            float v = acc[c][j];
            if (LEAKY) v = (v >= 0.f) ? v : 0.01f * v;
            r[j] = v;
        }
        *(float4*)(out + ((size_t)b * CO + co0 + c) * LL + l0) =
            make_float4(r[0], r[1], r[2], r[3]);
    }
}

// ---------------------------------------------------------------
// Weight prep: frag-linear bf16 for MFMA A-operand.
// ---------------------------------------------------------------
template<int CO_REAL, int NCOB>
__global__ __launch_bounds__(256) void k_wprep(const float* __restrict__ w,
        unsigned short* __restrict__ wp) {
    int idx = blockIdx.x * 256 + threadIdx.x;
    if (idx >= 15 * NCOB * 1024) return;
    int j = idx & 7;
    int lane = (idx >> 3) & 63;
    int cis = (idx >> 9) & 1;
    int rest = idx >> 10;
    int cob = rest % NCOB;
    int kk = rest / NCOB;
    int co = cob * 16 + (lane & 15);
    int ci = cis * 32 + ((lane >> 4) << 3) + j;
    float val = (co < CO_REAL) ? w[((size_t)co * 64 + ci) * KK + kk] : 0.f;
    wp[idx] = f2b(val);
}

// ---------------------------------------------------------------
// MFMA implicit-GEMM conv, K=15, CI=64, bf16 in.
// MODE 0: fp32 out. MODE 1: bf16 out. (No fused stats: device-scope
// atomic contention on 128 addrs x 256 blocks cost ~110us in R10.)
// ---------------------------------------------------------------
template<int CO_REAL, int NCOB, int MODE>
__global__ __launch_bounds__(256) void k_convmfma(
        const unsigned short* __restrict__ xt,
        const unsigned short* __restrict__ wp,
        const float* __restrict__ bias, void* __restrict__ outv) {
    __shared__ unsigned short in_lds[142 * 72];
    const int NCOT = NCOB / 4;
    int tid = threadIdx.x;
    int bid = blockIdx.x;
    int lt = bid & 31;
    int cot = (bid >> 5) % NCOT;
    int b = bid / (32 * NCOT);
    int l0 = lt * 128;
#pragma unroll
    for (int i = 0; i < 5; ++i) {
        int q = i * 256 + tid;
        if (q < 1136) {
            int r = q >> 3, c8 = (q & 7) * 8;
            int gl = l0 - 7 + r;
            s8v v = {0,0,0,0,0,0,0,0};
            if (gl >= 0 && gl < LL)
                v = *(const s8v*)&xt[((size_t)b * LL + gl) * 64 + c8];
            *(s8v*)&in_lds[r * 72 + c8] = v;
        }
    }
    __syncthreads();
    int lane = tid & 63, wv = tid >> 6;
    int corow = (lane >> 4) << 2;
    f4v acc[4][2];
#pragma unroll
    for (int mt = 0; mt < 4; ++mt) {
#pragma unroll
        for (int r = 0; r < 4; ++r) {
            int co = cot * 64 + mt * 16 + corow + r;
            float bv = (co < CO_REAL) ? bias[co] : 0.f;
            acc[mt][0][r] = bv;
            acc[mt][1][r] = bv;
        }
    }
    int bcol = lane & 15;
    int cig = (lane >> 4) << 3;
    for (int k = 0; k < KK; ++k) {
#pragma unroll
        for (int cis = 0; cis < 2; ++cis) {
            frag_u a[4], bf[2];
#pragma unroll
            for (int mt = 0; mt < 4; ++mt)
                a[mt].s = *(const s8v*)&wp[((((k * NCOB + cot * 4 + mt) * 2 + cis) << 9)
                                           + (lane << 3))];
#pragma unroll
            for (int nt = 0; nt < 2; ++nt)
                bf[nt].s = *(const s8v*)&in_lds[(wv * 32 + nt * 16 + bcol + k) * 72
                                               + cis * 32 + cig];
#pragma unroll
            for (int mt = 0; mt < 4; ++mt)
#pragma unroll
                for (int nt = 0; nt < 2; ++nt)
                    acc[mt][nt] = __builtin_amdgcn_mfma_f32_16x16x32_bf16(
                        a[mt].b, bf[nt].b, acc[mt][nt], 0, 0, 0);
        }
    }
#pragma unroll
    for (int mt = 0; mt < 4; ++mt)
#pragma unroll
        for (int nt = 0; nt < 2; ++nt) {
            int l = l0 + wv * 32 + nt * 16 + bcol;
#pragma unroll
            for (int r = 0; r < 4; ++r) {
                int co = cot * 64 + mt * 16 + corow + r;
                if (co < CO_REAL) {
                    if (MODE == 0)
                        ((float*)outv)[((size_t)b * CO_REAL + co) * LL + l] = acc[mt][nt][r];
                    else
                        ((unsigned short*)outv)[((size_t)b * CO_REAL + co) * LL + l]
                            = f2b(acc[mt][nt][r]);
                }
            }
        }
}

// ---------------------------------------------------------------
// BN partial sums (R7-proven: 512 blocks, 2 atomics each -> 8/addr).
// ---------------------------------------------------------------
__global__ __launch_bounds__(256) void k_bnpart(const float* __restrict__ xm,
        float* __restrict__ stats) {
    int c = blockIdx.x >> 3, b = blockIdx.x & 7;
    const float* p = xm + ((size_t)b * DD + c) * LL;
    int tid = threadIdx.x;
    float s = 0.f, ss = 0.f;
#pragma unroll
    for (int it = 0; it < 4; ++it) {
        float4 v = *(const float4*)(p + (size_t)(it * 256 + tid) * 4);
        s  += v.x + v.y + v.z + v.w;
        ss += v.x*v.x + v.y*v.y + v.z*v.z + v.w*v.w;
    }
    for (int o = 32; o > 0; o >>= 1) {
        s  += __shfl_down(s, o);
        ss += __shfl_down(ss, o);
    }
    __shared__ float red[8];
    int wid = tid >> 6;
    if ((tid & 63) == 0) { red[wid] = s; red[4 + wid] = ss; }
    __syncthreads();
    if (tid == 0) {
        atomicAdd(&stats[c], red[0] + red[1] + red[2] + red[3]);
        atomicAdd(&stats[64 + c], red[4] + red[5] + red[6] + red[7]);
    }
}

// ---------------------------------------------------------------
// in_proj GEMM: xz_bf16(32768,256) = A^T-view * W(256,64)^T
// ---------------------------------------------------------------
__global__ __launch_bounds__(256) void k_gemm_inproj(const float* __restrict__ A,
        const float* __restrict__ W, unsigned short* __restrict__ C) {
    __shared__ float At[64 * 132];
    __shared__ float Wt[64 * 132];
    int tid = threadIdx.x;
    int bid = blockIdx.x;
    int nb = bid & 1;
    int mb = bid >> 1;
    int row0 = mb * 128;
    int n0 = nb * 128;
    int b = row0 >> 12;
    int l0 = row0 & 4095;
#pragma unroll
    for (int it = 0; it < 8; ++it) {
        int idx = it * 256 + tid;
        int k = idx >> 5, m4 = (idx & 31) * 4;
        float4 v = *(const float4*)(A + ((size_t)b * DD + k) * LL + l0 + m4);
        *(float4*)&At[k * 132 + m4] = v;
    }
#pragma unroll
    for (int it = 0; it < 8; ++it) {
        int lin = it * 1024 + tid * 4;
        int n = lin >> 6, k = lin & 63;
        float4 v = *(const float4*)(W + (size_t)(n0 + n) * 64 + k);
        Wt[(k+0)*132 + n] = v.x; Wt[(k+1)*132 + n] = v.y;
        Wt[(k+2)*132 + n] = v.z; Wt[(k+3)*132 + n] = v.w;
    }
    __syncthreads();
    int tx = tid & 15, ty = tid >> 4;
    float acc[2][2][4][4] = {};
#pragma unroll 4
    for (int k = 0; k < 64; ++k) {
        float4 aLo = *(float4*)&At[k*132 + ty*4];
        float4 aHi = *(float4*)&At[k*132 + 64 + ty*4];
        float4 bLo = *(float4*)&Wt[k*132 + tx*4];
        float4 bHi = *(float4*)&Wt[k*132 + 64 + tx*4];
        float a0[4] = {aLo.x, aLo.y, aLo.z, aLo.w};
        float a1[4] = {aHi.x, aHi.y, aHi.z, aHi.w};
        float b0[4] = {bLo.x, bLo.y, bLo.z, bLo.w};
        float b1[4] = {bHi.x, bHi.y, bHi.z, bHi.w};
#pragma unroll
        for (int mm = 0; mm < 4; ++mm)
#pragma unroll
            for (int nn = 0; nn < 4; ++nn) {
                acc[0][0][mm][nn] += a0[mm] * b0[nn];
                acc[0][1][mm][nn] += a0[mm] * b1[nn];
                acc[1][0][mm][nn] += a1[mm] * b0[nn];
                acc[1][1][mm][nn] += a1[mm] * b1[nn];
            }
    }
#pragma unroll
    for (int qm = 0; qm < 2; ++qm)
#pragma unroll
        for (int mm = 0; mm < 4; ++mm) {
            int row = row0 + qm*64 + ty*4 + mm;
#pragma unroll
            for (int qn = 0; qn < 2; ++qn) {
                unsigned short o[4];
#pragma unroll
                for (int nn = 0; nn < 4; ++nn) o[nn] = f2b(acc[qm][qn][mm][nn]);
                *(uint2*)&C[(size_t)row * 256 + n0 + qn*64 + tx*4] = *(uint2*)o;
            }
        }
}

// ---------------------------------------------------------------
// x_proj GEMM with FUSED depthwise conv+silu.
// ---------------------------------------------------------------
template<int NW>
__global__ __launch_bounds__(256) void k_gemm64dw(
        const unsigned short* __restrict__ xzb,
        const float* __restrict__ dww, const float* __restrict__ dwb,
        const float* __restrict__ W, float* __restrict__ out) {
    __shared__ float At[64 * 132];
    __shared__ float Wt[64 * 68];
    __shared__ float sdw[128][4];
    __shared__ float sbias[128];
    int tid = threadIdx.x;
    int row0 = blockIdx.x * 128;
    int l0 = row0 & 4095;
    if (tid < 128) {
        *(float4*)&sdw[tid][0] = *(const float4*)(dww + tid * 4);
        sbias[tid] = dwb[tid];
    }
    int tx = tid & 15, ty = tid >> 4;
    float acc[2][4][4] = {};
#pragma unroll
    for (int kt = 0; kt < 2; ++kt) {
        __syncthreads();
#pragma unroll
        for (int it = 0; it < 4; ++it) {
            int task = it * 256 + tid;
            int m = task >> 3;
            int k8 = (task & 7) * 8;
            int d0 = kt * 64 + k8;
            float s[8];
#pragma unroll
            for (int j = 0; j < 8; ++j) s[j] = sbias[d0 + j];
#pragma unroll
            for (int tap = 0; tap < 4; ++tap) {
                if (l0 + m - 3 + tap >= 0) {
                    s8v xv = *(const s8v*)&xzb[(size_t)(row0 + m - 3 + tap) * 256 + d0];
#pragma unroll
                    for (int j = 0; j < 8; ++j)
                        s[j] += b2f((unsigned short)xv[j]) * sdw[d0 + j][tap];
                }
            }
#pragma unroll
            for (int j = 0; j < 8; ++j) {
                float v = s[j];
                At[(k8 + j) * 132 + m] = v / (1.f + __expf(-v));
            }
        }
#pragma unroll
        for (int it = 0; it < 4; ++it) {
            int lin = it * 1024 + tid * 4;
            int n = lin >> 6, k = lin & 63;
            float4 v = make_float4(0.f, 0.f, 0.f, 0.f);
            if (n < NW)
                v = *(const float4*)(W + (size_t)n * 128 + kt*64 + k);
            Wt[(k+0)*68 + n] = v.x; Wt[(k+1)*68 + n] = v.y;
            Wt[(k+2)*68 + n] = v.z; Wt[(k+3)*68 + n] = v.w;
        }
        __syncthreads();
#pragma unroll 4
        for (int k = 0; k < 64; ++k) {
            float4 aLo = *(float4*)&At[k*132 + ty*4];
            float4 aHi = *(float4*)&At[k*132 + 64 + ty*4];
            float4 b4  = *(float4*)&Wt[k*68 + tx*4];
            float a0[4] = {aLo.x, aLo.y, aLo.z, aLo.w};
            float a1[4] = {aHi.x, aHi.y, aHi.z, aHi.w};
            float bv[4] = {b4.x, b4.y, b4.z, b4.w};
#pragma unroll
            for (int mm = 0; mm < 4; ++mm)
#pragma unroll
                for (int nn = 0; nn < 4; ++nn) {
                    acc[0][mm][nn] += a0[mm] * bv[nn];
                    acc[1][mm][nn] += a1[mm] * bv[nn];
                }
        }
    }
#pragma unroll
    for (int qm = 0; qm < 2; ++qm)
#pragma unroll
        for (int mm = 0; mm < 4; ++mm) {
            int row = row0 + qm*64 + ty*4 + mm;
            *(float4*)(out + (size_t)row * 64 + tx*4) =
                make_float4(acc[qm][mm][0], acc[qm][mm][1],
                            acc[qm][mm][2], acc[qm][mm][3]);
        }
}

// ---------------------------------------------------------------
// out_proj GEMM (A = ym bf16) + residual + bf16 transposed write.
// ---------------------------------------------------------------
__global__ __launch_bounds__(256) void k_gemm64_tr(
        const unsigned short* __restrict__ A, const float* __restrict__ W,
        const float* __restrict__ res, unsigned short* __restrict__ out) {
    __shared__ float smem[13312];
    float* At = smem;
    float* Wt = smem + 64*132;
    int tid = threadIdx.x;
    int row0 = blockIdx.x * 128;
    int tx = tid & 15, ty = tid >> 4;
    int b = row0 >> 12, l0 = row0 & 4095;
    float acc[2][4][4] = {};
#pragma unroll
    for (int kt = 0; kt < 2; ++kt) {
        __syncthreads();
#pragma unroll
        for (int it = 0; it < 4; ++it) {
            int task = it * 256 + tid;
            int m = task >> 3;
            int k8 = (task & 7) * 8;
            s8v v = *(const s8v*)&A[(size_t)(row0 + m) * 128 + kt*64 + k8];
#pragma unroll
            for (int j = 0; j < 8; ++j)
                At[(k8 + j) * 132 + m] = b2f((unsigned short)v[j]);
        }
#pragma unroll
        for (int it = 0; it < 4; ++it) {
            int lin = it * 1024 + tid * 4;
            int n = lin >> 6, k = lin & 63;
            float4 v = *(const float4*)(W + (size_t)n * 128 + kt*64 + k);
            Wt[(k+0)*68 + n] = v.x; Wt[(k+1)*68 + n] = v.y;
            Wt[(k+2)*68 + n] = v.z; Wt[(k+3)*68 + n] = v.w;
        }
        __syncthreads();
#pragma unroll 4
        for (int k = 0; k < 64; ++k) {
            float4 aLo = *(float4*)&At[k*132 + ty*4];
            float4 aHi = *(float4*)&At[k*132 + 64 + ty*4];
            float4 b4  = *(float4*)&Wt[k*68 + tx*4];
            float a0[4] = {aLo.x, aLo.y, aLo.z, aLo.w};
            float a1[4] = {aHi.x, aHi.y, aHi.z, aHi.w};
            float bv[4] = {b4.x, b4.y, b4.z, b4.w};
#pragma unroll
            for (int mm = 0; mm < 4; ++mm)
#pragma unroll
                for (int nn = 0; nn < 4; ++nn) {
                    acc[0][mm][nn] += a0[mm] * bv[nn];
                    acc[1][mm][nn] += a1[mm] * bv[nn];
                }
        }
    }
    __syncthreads();
    float* tile = smem;                               // [128][68]
    unsigned short* resb = (unsigned short*)(smem + 8704);  // [128][72]
#pragma unroll
    for (int qm = 0; qm < 2; ++qm)
#pragma unroll
        for (int mm = 0; mm < 4; ++mm) {
            int lrow = qm*64 + ty*4 + mm;
            *(float4*)&tile[lrow*68 + tx*4] = make_float4(
                acc[qm][mm][0], acc[qm][mm][1], acc[qm][mm][2], acc[qm][mm][3]);
        }
#pragma unroll
    for (int it = 0; it < 8; ++it) {
        int idx = it * 256 + tid;
        int d = idx >> 5, l4 = (idx & 31) * 4;
        float4 rv = *(const float4*)(res + ((size_t)b * DD + d) * LL + l0 + l4);
        resb[(l4+0)*72 + d] = f2b(rv.x);
        resb[(l4+1)*72 + d] = f2b(rv.y);
        resb[(l4+2)*72 + d] = f2b(rv.z);
        resb[(l4+3)*72 + d] = f2b(rv.w);
    }
    __syncthreads();
#pragma unroll
    for (int it = 0; it < 4; ++it) {
        int idx = it * 256 + tid;
        int l = idx >> 3, c8 = (idx & 7) * 8;
        unsigned short o[8];
#pragma unroll
        for (int j = 0; j < 8; ++j)
            o[j] = f2b(tile[l*68 + c8 + j] + b2f(resb[l*72 + c8 + j]));
        *(s8v*)&out[((size_t)b * LL + l0 + l) * 64 + c8] = *(s8v*)o;
    }
}

// ---------------------------------------------------------------
// Scan phase 1: thread owns d; dwconv+silu + dt_proj fused.
// ---------------------------------------------------------------
__global__ __launch_bounds__(256) void k_scan1(
        const unsigned short* __restrict__ xzb, const float* __restrict__ dbl,
        const float* __restrict__ dww, const float* __restrict__ dwb,
        const float* __restrict__ dtw, const float* __restrict__ dtbias,
        const float* __restrict__ A_log, float* __restrict__ P,
        float* __restrict__ Q) {
    __shared__ float sdbl[2][CLEN][64];
    int tid = threadIdx.x;
    int bid = blockIdx.x;
    int b = bid >> 6;
    int cpair = bid & 63;
    int half = tid >> 7;
    int d = tid & 127;
    int c = cpair * 2 + half;
    {
        const float4* src = (const float4*)(dbl +
            ((size_t)b * LL + (size_t)cpair * 2 * CLEN) * 64);
        float4* dst = (float4*)&sdbl[0][0][0];
#pragma unroll
        for (int i = 0; i < 4; ++i) dst[i * 256 + tid] = src[i * 256 + tid];
    }
    __syncthreads();
    float4 w4 = *(const float4*)(dtw + d * 4);
    float dbias = dtbias[d];
    float4 cw = *(const float4*)(dww + d * 4);
    float cbias = dwb[d];
    float Ads[16], h[16], p[16];
#pragma unroll
    for (int s = 0; s < 16; ++s) {
        Ads[s] = -__expf(A_log[d * DSx + s]);
        h[s] = 0.f; p[s] = 1.f;
    }
    int l0 = c * CLEN;
    const unsigned short* px = xzb + ((size_t)b * LL + l0) * 256 + d;
    float w0 = 0.f, w1 = 0.f, w2 = 0.f;
    if (l0) { w0 = b2f(px[-768]); w1 = b2f(px[-512]); w2 = b2f(px[-256]); }
    for (int t = 0; t < CLEN; ++t) {
        float cur = b2f(px[(size_t)t * 256]);
        float sv = cbias + w0*cw.x + w1*cw.y + w2*cw.z + cur*cw.w;
        float xs = sv / (1.f + __expf(-sv));
        w0 = w1; w1 = w2; w2 = cur;
        float4 di = *(const float4*)&sdbl[half][t][0];
        float dtv = di.x*w4.x + di.y*w4.y + di.z*w4.z + di.w*w4.w + dbias;
        dtv = (dtv > 15.f) ? dtv : log1pf(__expf(dtv));
        float dx = dtv * xs;
#pragma unroll
        for (int s = 0; s < 16; ++s) {
            float da = __expf(dtv * Ads[s]);
            h[s] = da * h[s] + dx * sdbl[half][t][4 + s];
            p[s] *= da;
        }
    }
    float* Pp = P + (size_t)c * 16384 + (size_t)(b * 128 + d) * 16;
    float* Qp = Q + (size_t)c * 16384 + (size_t)(b * 128 + d) * 16;
#pragma unroll
    for (int s4 = 0; s4 < 4; ++s4) {
        *(float4*)(Pp + s4*4) = make_float4(p[s4*4], p[s4*4+1], p[s4*4+2], p[s4*4+3]);
        *(float4*)(Qp + s4*4) = make_float4(h[s4*4], h[s4*4+1], h[s4*4+2], h[s4*4+3]);
    }
}

// ---------------------------------------------------------------
// Scan phase 2: prefix over chunks + zero BN stats accum.
// ---------------------------------------------------------------
__global__ __launch_bounds__(256) void k_scan2(const float* __restrict__ P,
        const float* __restrict__ Q, float* __restrict__ Hin,
        float* __restrict__ stats) {
    int chain = blockIdx.x * 256 + threadIdx.x;  // 16384
    if (blockIdx.x == 0 && threadIdx.x < 128) stats[threadIdx.x] = 0.f;
    float carry = 0.f;
    for (int c = 0; c < NCH; ++c) {
        Hin[(size_t)c * 16384 + chain] = carry;
        carry = P[(size_t)c * 16384 + chain] * carry + Q[(size_t)c * 16384 + chain];
    }
}

// ---------------------------------------------------------------
// Scan phase 3: thread owns d; fused dwconv + dt + gate; ym bf16 out.
// ---------------------------------------------------------------
__global__ __launch_bounds__(256) void k_scan3(
        const unsigned short* __restrict__ xzb, const float* __restrict__ dbl,
        const float* __restrict__ dww, const float* __restrict__ dwb,
        const float* __restrict__ dtw, const float* __restrict__ dtbias,
        const float* __restrict__ A_log, const float* __restrict__ Hin,
        const float* __restrict__ Dssm, unsigned short* __restrict__ ymb) {
    __shared__ float sdbl[2][CLEN][64];
    int tid = threadIdx.x;
    int bid = blockIdx.x;
    int b = bid >> 6;
    int cpair = bid & 63;
    int half = tid >> 7;
    int d = tid & 127;
    int c = cpair * 2 + half;
    {
        const float4* src = (const float4*)(dbl +
            ((size_t)b * LL + (size_t)cpair * 2 * CLEN) * 64);
        float4* dst = (float4*)&sdbl[0][0][0];
#pragma unroll
        for (int i = 0; i < 4; ++i) dst[i * 256 + tid] = src[i * 256 + tid];
    }
    __syncthreads();
    float4 w4 = *(const float4*)(dtw + d * 4);
    float dbias = dtbias[d];
    float4 cw = *(const float4*)(dww + d * 4);
    float cbias = dwb[d];
    float Dv = Dssm[d];
    float Ads[16], h[16];
#pragma unroll
    for (int s = 0; s < 16; ++s)
        Ads[s] = -__expf(A_log[d * DSx + s]);
    const float* Hp = Hin + (size_t)c * 16384 + (size_t)(b * 128 + d) * 16;
#pragma unroll
    for (int s4 = 0; s4 < 4; ++s4) {
        float4 hv = *(const float4*)(Hp + s4*4);
        h[s4*4+0] = hv.x; h[s4*4+1] = hv.y; h[s4*4+2] = hv.z; h[s4*4+3] = hv.w;
    }
    int l0 = c * CLEN;
    size_t rowbase = (size_t)b * LL + l0;
    const unsigned short* px = xzb + rowbase * 256 + d;
    const unsigned short* pz = xzb + rowbase * 256 + 128 + d;
    unsigned short* pym = ymb + rowbase * 128 + d;
    float w0 = 0.f, w1 = 0.f, w2 = 0.f;
    if (l0) { w0 = b2f(px[-768]); w1 = b2f(px[-512]); w2 = b2f(px[-256]); }
    for (int t = 0; t < CLEN; ++t) {
        float cur = b2f(px[(size_t)t * 256]);
        float sv = cbias + w0*cw.x + w1*cw.y + w2*cw.z + cur*cw.w;
        float xs = sv / (1.f + __expf(-sv));
        w0 = w1; w1 = w2; w2 = cur;
        float4 di = *(const float4*)&sdbl[half][t][0];
        float dtv = di.x*w4.x + di.y*w4.y + di.z*w4.z + di.w*w4.w + dbias;
        dtv = (dtv > 15.f) ? dtv : log1pf(__expf(dtv));
        float dx = dtv * xs;
        float y0 = 0.f, y1 = 0.f;
#pragma unroll
        for (int s = 0; s < 8; ++s) {
            float da = __expf(dtv * Ads[s]);
            h[s] = da * h[s] + dx * sdbl[half][t][4 + s];
            y0 += h[s] * sdbl[half][t][20 + s];
        }
#pragma unroll
        for (int s = 8; s < 16; ++s) {
            float da = __expf(dtv * Ads[s]);
            h[s] = da * h[s] + dx * sdbl[half][t][4 + s];
            y1 += h[s] * sdbl[half][t][20 + s];
        }
        float y = y0 + y1 + xs * Dv;
        float zv = b2f(pz[(size_t)t * 256]);
        y *= zv / (1.f + __expf(-zv));
        pym[(size_t)t * 128] = f2b(y);
    }
}

// ---------------------------------------------------------------
// BN apply + residual + transpose -> bf16 (B,L,64).
// ---------------------------------------------------------------
__global__ __launch_bounds__(256) void k_bnapply_t(const float* __restrict__ xm,
        const float* __restrict__ stats, const float* __restrict__ gamma,
        const float* __restrict__ beta, const float* __restrict__ xin,
        unsigned short* __restrict__ xf) {
    __shared__ float t[64][65];
    int tid = threadIdx.x;
    int b = blockIdx.x >> 6;
    int l0 = (blockIdx.x & 63) * 64;
    const float inv = 1.f / (float)(BB * LL);
#pragma unroll
    for (int it = 0; it < 16; ++it) {
        int idx = it * 256 + tid;
        int c = idx >> 6, l = idx & 63;
        float mean = stats[c] * inv;
        float var  = stats[64 + c] * inv - mean * mean;
        float g = gamma[c] * rsqrtf(var + 1e-5f);
        float sh = beta[c] - mean * g;
        size_t addr = ((size_t)b * DD + c) * LL + l0 + l;
        t[c][l] = xm[addr] * g + sh + xin[addr];
    }
    __syncthreads();
#pragma unroll
    for (int it = 0; it < 2; ++it) {
        int idx = it * 256 + tid;
        int l = idx >> 3, c8 = (idx & 7) * 8;
        unsigned short o[8];
#pragma unroll
        for (int j = 0; j < 8; ++j) o[j] = f2b(t[c8 + j][l]);
        *(s8v*)&xf[((size_t)b * LL + l0 + l) * 64 + c8] = *(s8v*)o;
    }
}

// ---------------------------------------------------------------
// PixelShuffle(r=10) + linear upsample + add (xp bf16 in).
// ---------------------------------------------------------------
__global__ __launch_bounds__(256) void k_final(const unsigned short* __restrict__ xp,
        const float* __restrict__ x, float* __restrict__ out) {
    __shared__ float xps[10][257];
    __shared__ float xr[258];
    int tid = threadIdx.x;
    int bid = blockIdx.x;
    int lt = bid & 15;
    int c = (bid >> 4) % 12;
    int b = bid / (16 * 12);
    int l0 = lt * 256;
#pragma unroll
    for (int r = 0; r < 10; ++r)
        xps[r][tid] = b2f(xp[((size_t)b * 120 + r * 12 + c) * LL + l0 + tid]);
    const float* xrow = x + ((size_t)b * 12 + c) * LL;
    for (int i = tid; i < 258; i += 256) {
        int g = l0 - 1 + i;
        g = (g < 0) ? 0 : ((g > LL - 1) ? LL - 1 : g);
        xr[i] = xrow[g];
    }
    __syncthreads();
    size_t obase = ((size_t)b * 12 + c) * OUTL + (size_t)l0 * 10;
#pragma unroll
    for (int u = 0; u < 10; ++u) {
        int j = u * 256 + tid;
        int jg = l0 * 10 + j;
        int l = j / 10, r = j - l * 10;
        float ps = xps[r][l];
        float src = ((float)jg + 0.5f) * 0.1f - 0.5f;
        src = fmaxf(src, 0.f);
        int i0 = (int)src;
        if (i0 > LL - 1) i0 = LL - 1;
        int i1 = (i0 + 1 < LL) ? i0 + 1 : LL - 1;
        float frac = src - (float)i0;
        float up = xr[i0 - l0 + 1] * (1.f - frac) + xr[i1 - l0 + 1] * frac;
        out[obase + j] = ps + up;
    }
}

// ---------------------------------------------------------------
extern "C" void kernel_launch(void* const* d_in, const int* in_sizes, int n_in,
                              void* d_out, int out_size, void* d_ws, size_t ws_size,
                              hipStream_t stream) {
    const float* x          = (const float*)d_in[0];
    const float* conv_in_w  = (const float*)d_in[1];
    const float* conv_in_b  = (const float*)d_in[2];
    const float* in_proj_w  = (const float*)d_in[3];
    const float* dw_w       = (const float*)d_in[4];
    const float* dw_b       = (const float*)d_in[5];
    const float* x_proj_w   = (const float*)d_in[6];
    const float* dt_w       = (const float*)d_in[7];
    const float* dt_b       = (const float*)d_in[8];
    const float* A_log      = (const float*)d_in[9];
    const float* Dssm       = (const float*)d_in[10];
    const float* out_proj_w = (const float*)d_in[11];
    const float* cm_w       = (const float*)d_in[12];
    const float* cm_b       = (const float*)d_in[13];
    const float* bn_g       = (const float*)d_in[14];
    const float* bn_be      = (const float*)d_in[15];
    const float* ps_w       = (const float*)d_in[16];
    const float* ps_b       = (const float*)d_in[17];

    // Workspace layout (float offsets, NO overlaps):
    float* ws = (float*)d_ws;
    float* xin_bdl = ws;                                     // [0, 2097152)
    unsigned short* xzb = (unsigned short*)(ws + 2097152);   // [2097152, 6291456)
    float* dbl64   = ws + 6291456;                           // [.., 8388608)
    float* P       = ws + 8388608;                           // [.., 10485760)
    float* Q       = ws + 10485760;                          // [.., 12582912)
    float* Hin     = ws + 12582912;                          // [.., 14680064)
    float* stats   = ws + 14680064;                          // 128
    unsigned short* ymb = (unsigned short*)(ws + 14680192);  // [.., 16777344)
    unsigned short* xmt = (unsigned short*)(ws + 16777344);  // [.., 17825920)
    float* xmerge  = ws + 17825920;                          // [.., 19923072)
    unsigned short* xf  = (unsigned short*)(ws + 19923072);  // [.., 20971648)
    unsigned short* wp_ps = (unsigned short*)(ws + 20971648);
    unsigned short* wp_mg = (unsigned short*)(ws + 21033088);
    unsigned short* xpb = (unsigned short*)(ws + 21063808);  // [.., 23029888)

    k_conv<CIN, 64, 2, true><<<1024, 256, 0, stream>>>(x, conv_in_w, conv_in_b, xin_bdl);
    k_gemm_inproj<<<512, 256, 0, stream>>>(xin_bdl, in_proj_w, xzb);
    k_gemm64dw<36><<<256, 256, 0, stream>>>(xzb, dw_w, dw_b, x_proj_w, dbl64);
    k_scan1<<<512, 256, 0, stream>>>(xzb, dbl64, dw_w, dw_b, dt_w, dt_b, A_log, P, Q);
    k_scan2<<<64, 256, 0, stream>>>(P, Q, Hin, stats);
    k_scan3<<<512, 256, 0, stream>>>(xzb, dbl64, dw_w, dw_b, dt_w, dt_b, A_log, Hin,
                                     Dssm, ymb);
    k_wprep<120, 8><<<480, 256, 0, stream>>>(ps_w, wp_ps);
    k_wprep<64, 4><<<240, 256, 0, stream>>>(cm_w, wp_mg);
    k_gemm64_tr<<<256, 256, 0, stream>>>(ymb, out_proj_w, xin_bdl, xmt);
    k_convmfma<64, 4, 0><<<256, 256, 0, stream>>>(xmt, wp_mg, cm_b, xmerge);
    k_bnpart<<<512, 256, 0, stream>>>(xmerge, stats);
    k_bnapply_t<<<512, 256, 0, stream>>>(xmerge, stats, bn_g, bn_be, xin_bdl, xf);
    k_convmfma<120, 8, 1><<<512, 256, 0, stream>>>(xf, wp_ps, ps_b, xpb);
    k_final<<<1536, 256, 0, stream>>>(xpb, x, (float*)d_out);
}

// Round 12
// 304.383 us; speedup vs baseline: 1.3990x; 1.0467x over previous
//
#include <hip/hip_runtime.h>
#include <math.h>

#define BB 8
#define CIN 12
#define LL 4096
#define DD 64
#define DIx 128
#define DSx 16
#define RR 10
#define KK 15
#define NCH 256     // scan chunks
#define CLEN 16     // LL/NCH
#define OUTL 40960  // LL*RR

typedef __attribute__((ext_vector_type(8))) short s8v;
typedef __attribute__((ext_vector_type(8))) __bf16 b8v;
typedef __attribute__((ext_vector_type(4))) float f4v;
union frag_u { s8v s; b8v b; };

__device__ __forceinline__ unsigned short f2b(float f) {
    unsigned int u = __float_as_uint(f);
    u = (u + 0x7fffu + ((u >> 16) & 1u)) >> 16;
    return (unsigned short)u;
}
__device__ __forceinline__ float b2f(unsigned short h) {
    return __uint_as_float(((unsigned int)h) << 16);
}

// ---------------------------------------------------------------
// Direct conv1d fp32 (conv_in, CI=12).
// ---------------------------------------------------------------
template<int CI, int CO, int COT, bool LEAKY>
__global__ __launch_bounds__(256) void k_conv(const float* __restrict__ in,
        const float* __restrict__ w, const float* __restrict__ bias,
        float* __restrict__ out) {
    const int LT = 1024;
    int tid = threadIdx.x;
    int bid = blockIdx.x;
    const int nlt = LL / LT;
    const int ncog = CO / COT;
    int lt = bid % nlt;
    int cog = (bid / nlt) % ncog;
    int b = bid / (nlt * ncog);
    int l0 = lt * LT + tid * 4;
    int co0 = cog * COT;

    float acc[COT][4];
#pragma unroll
    for (int c = 0; c < COT; ++c) {
        float bv = bias[co0 + c];
#pragma unroll
        for (int j = 0; j < 4; ++j) acc[c][j] = bv;
    }
    for (int ci = 0; ci < CI; ++ci) {
        const float* inp = in + ((size_t)b * CI + ci) * LL;
        float in20[20];
#pragma unroll
        for (int q = 0; q < 5; ++q) {
            int gi = l0 - 8 + q * 4;
            if (gi >= 0 && gi + 3 < LL) {
                float4 v = *(const float4*)(inp + gi);
                in20[q*4+0] = v.x; in20[q*4+1] = v.y;
                in20[q*4+2] = v.z; in20[q*4+3] = v.w;
            } else {
#pragma unroll
                for (int j = 0; j < 4; ++j) {
                    int g = gi + j;
                    in20[q*4+j] = (g >= 0 && g < LL) ? inp[g] : 0.f;
                }
            }
        }
#pragma unroll
        for (int c = 0; c < COT; ++c) {
            const float* wp = w + ((size_t)(co0 + c) * CI + ci) * KK;
#pragma unroll
            for (int k = 0; k < KK; ++k) {
                float wv = wp[k];
#pragma unroll
                for (int j = 0; j < 4; ++j)
                    acc[c][j] += wv * in20[j + k + 1];
            }
        }
    }
#pragma unroll
    for (int c = 0; c < COT; ++c) {
        float r[4];
#pragma unroll
        for (int j = 0; j < 4; ++j) {
            float v = acc[c][j];
            if (LEAKY) v = (v >= 0.f) ? v : 0.01f * v;
            r[j] = v;
        }
        *(float4*)(out + ((size_t)b * CO + co0 + c) * LL + l0) =
            make_float4(r[0], r[1], r[2], r[3]);
    }
}

// ---------------------------------------------------------------
// Weight prep: frag-linear bf16 for MFMA A-operand.
// ---------------------------------------------------------------
template<int CO_REAL, int NCOB>
__global__ __launch_bounds__(256) void k_wprep(const float* __restrict__ w,
        unsigned short* __restrict__ wp) {
    int idx = blockIdx.x * 256 + threadIdx.x;
    if (idx >= 15 * NCOB * 1024) return;
    int j = idx & 7;
    int lane = (idx >> 3) & 63;
    int cis = (idx >> 9) & 1;
    int rest = idx >> 10;
    int cob = rest % NCOB;
    int kk = rest / NCOB;
    int co = cob * 16 + (lane & 15);
    int ci = cis * 32 + ((lane >> 4) << 3) + j;
    float val = (co < CO_REAL) ? w[((size_t)co * 64 + ci) * KK + kk] : 0.f;
    wp[idx] = f2b(val);
}

// ---------------------------------------------------------------
// MFMA implicit-GEMM conv, K=15, CI=64, bf16 in.
// MODE 0: fp32 out. MODE 1: bf16 out.
// ---------------------------------------------------------------
template<int CO_REAL, int NCOB, int MODE>
__global__ __launch_bounds__(256) void k_convmfma(
        const unsigned short* __restrict__ xt,
        const unsigned short* __restrict__ wp,
        const float* __restrict__ bias, void* __restrict__ outv) {
    __shared__ unsigned short in_lds[142 * 72];
    const int NCOT = NCOB / 4;
    int tid = threadIdx.x;
    int bid = blockIdx.x;
    int lt = bid & 31;
    int cot = (bid >> 5) % NCOT;
    int b = bid / (32 * NCOT);
    int l0 = lt * 128;
#pragma unroll
    for (int i = 0; i < 5; ++i) {
        int q = i * 256 + tid;
        if (q < 1136) {
            int r = q >> 3, c8 = (q & 7) * 8;
            int gl = l0 - 7 + r;
            s8v v = {0,0,0,0,0,0,0,0};
            if (gl >= 0 && gl < LL)
                v = *(const s8v*)&xt[((size_t)b * LL + gl) * 64 + c8];
            *(s8v*)&in_lds[r * 72 + c8] = v;
        }
    }
    __syncthreads();
    int lane = tid & 63, wv = tid >> 6;
    int corow = (lane >> 4) << 2;
    f4v acc[4][2];
#pragma unroll
    for (int mt = 0; mt < 4; ++mt) {
#pragma unroll
        for (int r = 0; r < 4; ++r) {
            int co = cot * 64 + mt * 16 + corow + r;
            float bv = (co < CO_REAL) ? bias[co] : 0.f;
            acc[mt][0][r] = bv;
            acc[mt][1][r] = bv;
        }
    }
    int bcol = lane & 15;
    int cig = (lane >> 4) << 3;
    for (int k = 0; k < KK; ++k) {
#pragma unroll
        for (int cis = 0; cis < 2; ++cis) {
            frag_u a[4], bf[2];
#pragma unroll
            for (int mt = 0; mt < 4; ++mt)
                a[mt].s = *(const s8v*)&wp[((((k * NCOB + cot * 4 + mt) * 2 + cis) << 9)
                                           + (lane << 3))];
#pragma unroll
            for (int nt = 0; nt < 2; ++nt)
                bf[nt].s = *(const s8v*)&in_lds[(wv * 32 + nt * 16 + bcol + k) * 72
                                               + cis * 32 + cig];
#pragma unroll
            for (int mt = 0; mt < 4; ++mt)
#pragma unroll
                for (int nt = 0; nt < 2; ++nt)
                    acc[mt][nt] = __builtin_amdgcn_mfma_f32_16x16x32_bf16(
                        a[mt].b, bf[nt].b, acc[mt][nt], 0, 0, 0);
        }
    }
#pragma unroll
    for (int mt = 0; mt < 4; ++mt)
#pragma unroll
        for (int nt = 0; nt < 2; ++nt) {
            int l = l0 + wv * 32 + nt * 16 + bcol;
#pragma unroll
            for (int r = 0; r < 4; ++r) {
                int co = cot * 64 + mt * 16 + corow + r;
                if (co < CO_REAL) {
                    if (MODE == 0)
                        ((float*)outv)[((size_t)b * CO_REAL + co) * LL + l] = acc[mt][nt][r];
                    else
                        ((unsigned short*)outv)[((size_t)b * CO_REAL + co) * LL + l]
                            = f2b(acc[mt][nt][r]);
                }
            }
        }
}

// ---------------------------------------------------------------
// BN partial sums (512 blocks, 2 atomics each -> 8/addr).
// ---------------------------------------------------------------
__global__ __launch_bounds__(256) void k_bnpart(const float* __restrict__ xm,
        float* __restrict__ stats) {
    int c = blockIdx.x >> 3, b = blockIdx.x & 7;
    const float* p = xm + ((size_t)b * DD + c) * LL;
    int tid = threadIdx.x;
    float s = 0.f, ss = 0.f;
#pragma unroll
    for (int it = 0; it < 4; ++it) {
        float4 v = *(const float4*)(p + (size_t)(it * 256 + tid) * 4);
        s  += v.x + v.y + v.z + v.w;
        ss += v.x*v.x + v.y*v.y + v.z*v.z + v.w*v.w;
    }
    for (int o = 32; o > 0; o >>= 1) {
        s  += __shfl_down(s, o);
        ss += __shfl_down(ss, o);
    }
    __shared__ float red[8];
    int wid = tid >> 6;
    if ((tid & 63) == 0) { red[wid] = s; red[4 + wid] = ss; }
    __syncthreads();
    if (tid == 0) {
        atomicAdd(&stats[c], red[0] + red[1] + red[2] + red[3]);
        atomicAdd(&stats[64 + c], red[4] + red[5] + red[6] + red[7]);
    }
}

// ---------------------------------------------------------------
// in_proj GEMM: xz_bf16(32768,256) = A^T-view * W(256,64)^T
// ---------------------------------------------------------------
__global__ __launch_bounds__(256) void k_gemm_inproj(const float* __restrict__ A,
        const float* __restrict__ W, unsigned short* __restrict__ C) {
    __shared__ float At[64 * 132];
    __shared__ float Wt[64 * 132];
    int tid = threadIdx.x;
    int bid = blockIdx.x;
    int nb = bid & 1;
    int mb = bid >> 1;
    int row0 = mb * 128;
    int n0 = nb * 128;
    int b = row0 >> 12;
    int l0 = row0 & 4095;
#pragma unroll
    for (int it = 0; it < 8; ++it) {
        int idx = it * 256 + tid;
        int k = idx >> 5, m4 = (idx & 31) * 4;
        float4 v = *(const float4*)(A + ((size_t)b * DD + k) * LL + l0 + m4);
        *(float4*)&At[k * 132 + m4] = v;
    }
#pragma unroll
    for (int it = 0; it < 8; ++it) {
        int lin = it * 1024 + tid * 4;
        int n = lin >> 6, k = lin & 63;
        float4 v = *(const float4*)(W + (size_t)(n0 + n) * 64 + k);
        Wt[(k+0)*132 + n] = v.x; Wt[(k+1)*132 + n] = v.y;
        Wt[(k+2)*132 + n] = v.z; Wt[(k+3)*132 + n] = v.w;
    }
    __syncthreads();
    int tx = tid & 15, ty = tid >> 4;
    float acc[2][2][4][4] = {};
#pragma unroll 4
    for (int k = 0; k < 64; ++k) {
        float4 aLo = *(float4*)&At[k*132 + ty*4];
        float4 aHi = *(float4*)&At[k*132 + 64 + ty*4];
        float4 bLo = *(float4*)&Wt[k*132 + tx*4];
        float4 bHi = *(float4*)&Wt[k*132 + 64 + tx*4];
        float a0[4] = {aLo.x, aLo.y, aLo.z, aLo.w};
        float a1[4] = {aHi.x, aHi.y, aHi.z, aHi.w};
        float b0[4] = {bLo.x, bLo.y, bLo.z, bLo.w};
        float b1[4] = {bHi.x, bHi.y, bHi.z, bHi.w};
#pragma unroll
        for (int mm = 0; mm < 4; ++mm)
#pragma unroll
            for (int nn = 0; nn < 4; ++nn) {
                acc[0][0][mm][nn] += a0[mm] * b0[nn];
                acc[0][1][mm][nn] += a0[mm] * b1[nn];
                acc[1][0][mm][nn] += a1[mm] * b0[nn];
                acc[1][1][mm][nn] += a1[mm] * b1[nn];
            }
    }
#pragma unroll
    for (int qm = 0; qm < 2; ++qm)
#pragma unroll
        for (int mm = 0; mm < 4; ++mm) {
            int row = row0 + qm*64 + ty*4 + mm;
#pragma unroll
            for (int qn = 0; qn < 2; ++qn) {
                unsigned short o[4];
#pragma unroll
                for (int nn = 0; nn < 4; ++nn) o[nn] = f2b(acc[qm][qn][mm][nn]);
                *(uint2*)&C[(size_t)row * 256 + n0 + qn*64 + tx*4] = *(uint2*)o;
            }
        }
}

// ---------------------------------------------------------------
// x_proj GEMM with FUSED depthwise conv+silu.
// ---------------------------------------------------------------
template<int NW>
__global__ __launch_bounds__(256) void k_gemm64dw(
        const unsigned short* __restrict__ xzb,
        const float* __restrict__ dww, const float* __restrict__ dwb,
        const float* __restrict__ W, float* __restrict__ out) {
    __shared__ float At[64 * 132];
    __shared__ float Wt[64 * 68];
    __shared__ float sdw[128][4];
    __shared__ float sbias[128];
    int tid = threadIdx.x;
    int row0 = blockIdx.x * 128;
    int l0 = row0 & 4095;
    if (tid < 128) {
        *(float4*)&sdw[tid][0] = *(const float4*)(dww + tid * 4);
        sbias[tid] = dwb[tid];
    }
    int tx = tid & 15, ty = tid >> 4;
    float acc[2][4][4] = {};
#pragma unroll
    for (int kt = 0; kt < 2; ++kt) {
        __syncthreads();
#pragma unroll
        for (int it = 0; it < 4; ++it) {
            int task = it * 256 + tid;
            int m = task >> 3;
            int k8 = (task & 7) * 8;
            int d0 = kt * 64 + k8;
            float s[8];
#pragma unroll
            for (int j = 0; j < 8; ++j) s[j] = sbias[d0 + j];
#pragma unroll
            for (int tap = 0; tap < 4; ++tap) {
                if (l0 + m - 3 + tap >= 0) {
                    s8v xv = *(const s8v*)&xzb[(size_t)(row0 + m - 3 + tap) * 256 + d0];
#pragma unroll
                    for (int j = 0; j < 8; ++j)
                        s[j] += b2f((unsigned short)xv[j]) * sdw[d0 + j][tap];
                }
            }
#pragma unroll
            for (int j = 0; j < 8; ++j) {
                float v = s[j];
                At[(k8 + j) * 132 + m] = v / (1.f + __expf(-v));
            }
        }
#pragma unroll
        for (int it = 0; it < 4; ++it) {
            int lin = it * 1024 + tid * 4;
            int n = lin >> 6, k = lin & 63;
            float4 v = make_float4(0.f, 0.f, 0.f, 0.f);
            if (n < NW)
                v = *(const float4*)(W + (size_t)n * 128 + kt*64 + k);
            Wt[(k+0)*68 + n] = v.x; Wt[(k+1)*68 + n] = v.y;
            Wt[(k+2)*68 + n] = v.z; Wt[(k+3)*68 + n] = v.w;
        }
        __syncthreads();
#pragma unroll 4
        for (int k = 0; k < 64; ++k) {
            float4 aLo = *(float4*)&At[k*132 + ty*4];
            float4 aHi = *(float4*)&At[k*132 + 64 + ty*4];
            float4 b4  = *(float4*)&Wt[k*68 + tx*4];
            float a0[4] = {aLo.x, aLo.y, aLo.z, aLo.w};
            float a1[4] = {aHi.x, aHi.y, aHi.z, aHi.w};
            float bv[4] = {b4.x, b4.y, b4.z, b4.w};
#pragma unroll
            for (int mm = 0; mm < 4; ++mm)
#pragma unroll
                for (int nn = 0; nn < 4; ++nn) {
                    acc[0][mm][nn] += a0[mm] * bv[nn];
                    acc[1][mm][nn] += a1[mm] * bv[nn];
                }
        }
    }
#pragma unroll
    for (int qm = 0; qm < 2; ++qm)
#pragma unroll
        for (int mm = 0; mm < 4; ++mm) {
            int row = row0 + qm*64 + ty*4 + mm;
            *(float4*)(out + (size_t)row * 64 + tx*4) =
                make_float4(acc[qm][mm][0], acc[qm][mm][1],
                            acc[qm][mm][2], acc[qm][mm][3]);
        }
}

// ---------------------------------------------------------------
// out_proj GEMM (A = ym bf16) + residual + bf16 transposed write.
// ---------------------------------------------------------------
__global__ __launch_bounds__(256) void k_gemm64_tr(
        const unsigned short* __restrict__ A, const float* __restrict__ W,
        const float* __restrict__ res, unsigned short* __restrict__ out) {
    __shared__ float smem[13312];
    float* At = smem;
    float* Wt = smem + 64*132;
    int tid = threadIdx.x;
    int row0 = blockIdx.x * 128;
    int tx = tid & 15, ty = tid >> 4;
    int b = row0 >> 12, l0 = row0 & 4095;
    float acc[2][4][4] = {};
#pragma unroll
    for (int kt = 0; kt < 2; ++kt) {
        __syncthreads();
#pragma unroll
        for (int it = 0; it < 4; ++it) {
            int task = it * 256 + tid;
            int m = task >> 3;
            int k8 = (task & 7) * 8;
            s8v v = *(const s8v*)&A[(size_t)(row0 + m) * 128 + kt*64 + k8];
#pragma unroll
            for (int j = 0; j < 8; ++j)
                At[(k8 + j) * 132 + m] = b2f((unsigned short)v[j]);
        }
#pragma unroll
        for (int it = 0; it < 4; ++it) {
            int lin = it * 1024 + tid * 4;
            int n = lin >> 6, k = lin & 63;
            float4 v = *(const float4*)(W + (size_t)n * 128 + kt*64 + k);
            Wt[(k+0)*68 + n] = v.x; Wt[(k+1)*68 + n] = v.y;
            Wt[(k+2)*68 + n] = v.z; Wt[(k+3)*68 + n] = v.w;
        }
        __syncthreads();
#pragma unroll 4
        for (int k = 0; k < 64; ++k) {
            float4 aLo = *(float4*)&At[k*132 + ty*4];
            float4 aHi = *(float4*)&At[k*132 + 64 + ty*4];
            float4 b4  = *(float4*)&Wt[k*68 + tx*4];
            float a0[4] = {aLo.x, aLo.y, aLo.z, aLo.w};
            float a1[4] = {aHi.x, aHi.y, aHi.z, aHi.w};
            float bv[4] = {b4.x, b4.y, b4.z, b4.w};
#pragma unroll
            for (int mm = 0; mm < 4; ++mm)
#pragma unroll
                for (int nn = 0; nn < 4; ++nn) {
                    acc[0][mm][nn] += a0[mm] * bv[nn];
                    acc[1][mm][nn] += a1[mm] * bv[nn];
                }
        }
    }
    __syncthreads();
    float* tile = smem;                               // [128][68]
    unsigned short* resb = (unsigned short*)(smem + 8704);  // [128][72]
#pragma unroll
    for (int qm = 0; qm < 2; ++qm)
#pragma unroll
        for (int mm = 0; mm < 4; ++mm) {
            int lrow = qm*64 + ty*4 + mm;
            *(float4*)&tile[lrow*68 + tx*4] = make_float4(
                acc[qm][mm][0], acc[qm][mm][1], acc[qm][mm][2], acc[qm][mm][3]);
        }
#pragma unroll
    for (int it = 0; it < 8; ++it) {
        int idx = it * 256 + tid;
        int d = idx >> 5, l4 = (idx & 31) * 4;
        float4 rv = *(const float4*)(res + ((size_t)b * DD + d) * LL + l0 + l4);
        resb[(l4+0)*72 + d] = f2b(rv.x);
        resb[(l4+1)*72 + d] = f2b(rv.y);
        resb[(l4+2)*72 + d] = f2b(rv.z);
        resb[(l4+3)*72 + d] = f2b(rv.w);
    }
    __syncthreads();
#pragma unroll
    for (int it = 0; it < 4; ++it) {
        int idx = it * 256 + tid;
        int l = idx >> 3, c8 = (idx & 7) * 8;
        unsigned short o[8];
#pragma unroll
        for (int j = 0; j < 8; ++j)
            o[j] = f2b(tile[l*68 + c8 + j] + b2f(resb[l*72 + c8 + j]));
        *(s8v*)&out[((size_t)b * LL + l0 + l) * 64 + c8] = *(s8v*)o;
    }
}

// ---------------------------------------------------------------
// Scan phase 1: thread owns d; dwconv+silu + dt_proj fused.
// exp2-based dA (Ads pre-scaled by log2e); fast softplus.
// ---------------------------------------------------------------
__global__ __launch_bounds__(256) void k_scan1(
        const unsigned short* __restrict__ xzb, const float* __restrict__ dbl,
        const float* __restrict__ dww, const float* __restrict__ dwb,
        const float* __restrict__ dtw, const float* __restrict__ dtbias,
        const float* __restrict__ A_log, float* __restrict__ P,
        float* __restrict__ Q) {
    __shared__ float sdbl[2][CLEN][64];
    int tid = threadIdx.x;
    int bid = blockIdx.x;
    int b = bid >> 7;
    int cpair = bid & 127;
    int half = tid >> 7;
    int d = tid & 127;
    int c = cpair * 2 + half;
    {
        const float4* src = (const float4*)(dbl +
            ((size_t)b * LL + (size_t)cpair * 2 * CLEN) * 64);
        float4* dst = (float4*)&sdbl[0][0][0];
#pragma unroll
        for (int i = 0; i < 2; ++i) dst[i * 256 + tid] = src[i * 256 + tid];
    }
    __syncthreads();
    float4 w4 = *(const float4*)(dtw + d * 4);
    float dbias = dtbias[d];
    float4 cw = *(const float4*)(dww + d * 4);
    float cbias = dwb[d];
    const float LOG2E = 1.4426950408889634f;
    float Ads2[16], h[16], p[16];
#pragma unroll
    for (int s = 0; s < 16; ++s) {
        Ads2[s] = -__expf(A_log[d * DSx + s]) * LOG2E;
        h[s] = 0.f; p[s] = 1.f;
    }
    int l0 = c * CLEN;
    const unsigned short* px = xzb + ((size_t)b * LL + l0) * 256 + d;
    float w0 = 0.f, w1 = 0.f, w2 = 0.f;
    if (l0) { w0 = b2f(px[-768]); w1 = b2f(px[-512]); w2 = b2f(px[-256]); }
    for (int t = 0; t < CLEN; ++t) {
        float cur = b2f(px[(size_t)t * 256]);
        float sv = cbias + w0*cw.x + w1*cw.y + w2*cw.z + cur*cw.w;
        float xs = sv / (1.f + __expf(-sv));
        w0 = w1; w1 = w2; w2 = cur;
        float4 di = *(const float4*)&sdbl[half][t][0];
        float dtv = di.x*w4.x + di.y*w4.y + di.z*w4.z + di.w*w4.w + dbias;
        dtv = (dtv > 15.f) ? dtv : __logf(1.f + __expf(dtv));
        float dx = dtv * xs;
#pragma unroll
        for (int s = 0; s < 16; ++s) {
            float da = __builtin_amdgcn_exp2f(dtv * Ads2[s]);
            h[s] = da * h[s] + dx * sdbl[half][t][4 + s];
            p[s] *= da;
        }
    }
    float* Pp = P + (size_t)c * 16384 + (size_t)(b * 128 + d) * 16;
    float* Qp = Q + (size_t)c * 16384 + (size_t)(b * 128 + d) * 16;
#pragma unroll
    for (int s4 = 0; s4 < 4; ++s4) {
        *(float4*)(Pp + s4*4) = make_float4(p[s4*4], p[s4*4+1], p[s4*4+2], p[s4*4+3]);
        *(float4*)(Qp + s4*4) = make_float4(h[s4*4], h[s4*4+1], h[s4*4+2], h[s4*4+3]);
    }
}

// ---------------------------------------------------------------
// Scan phase 2: prefix over chunks + zero BN stats accum.
// ---------------------------------------------------------------
__global__ __launch_bounds__(256) void k_scan2(const float* __restrict__ P,
        const float* __restrict__ Q, float* __restrict__ Hin,
        float* __restrict__ stats) {
    int chain = blockIdx.x * 256 + threadIdx.x;  // 16384
    if (blockIdx.x == 0 && threadIdx.x < 128) stats[threadIdx.x] = 0.f;
    float carry = 0.f;
    for (int c = 0; c < NCH; ++c) {
        Hin[(size_t)c * 16384 + chain] = carry;
        carry = P[(size_t)c * 16384 + chain] * carry + Q[(size_t)c * 16384 + chain];
    }
}

// ---------------------------------------------------------------
// Scan phase 3: thread owns d; fused dwconv + dt + gate; ym bf16 out.
// ---------------------------------------------------------------
__global__ __launch_bounds__(256) void k_scan3(
        const unsigned short* __restrict__ xzb, const float* __restrict__ dbl,
        const float* __restrict__ dww, const float* __restrict__ dwb,
        const float* __restrict__ dtw, const float* __restrict__ dtbias,
        const float* __restrict__ A_log, const float* __restrict__ Hin,
        const float* __restrict__ Dssm, unsigned short* __restrict__ ymb) {
    __shared__ float sdbl[2][CLEN][64];
    int tid = threadIdx.x;
    int bid = blockIdx.x;
    int b = bid >> 7;
    int cpair = bid & 127;
    int half = tid >> 7;
    int d = tid & 127;
    int c = cpair * 2 + half;
    {
        const float4* src = (const float4*)(dbl +
            ((size_t)b * LL + (size_t)cpair * 2 * CLEN) * 64);
        float4* dst = (float4*)&sdbl[0][0][0];
#pragma unroll
        for (int i = 0; i < 2; ++i) dst[i * 256 + tid] = src[i * 256 + tid];
    }
    __syncthreads();
    float4 w4 = *(const float4*)(dtw + d * 4);
    float dbias = dtbias[d];
    float4 cw = *(const float4*)(dww + d * 4);
    float cbias = dwb[d];
    float Dv = Dssm[d];
    const float LOG2E = 1.4426950408889634f;
    float Ads2[16], h[16];
#pragma unroll
    for (int s = 0; s < 16; ++s)
        Ads2[s] = -__expf(A_log[d * DSx + s]) * LOG2E;
    const float* Hp = Hin + (size_t)c * 16384 + (size_t)(b * 128 + d) * 16;
#pragma unroll
    for (int s4 = 0; s4 < 4; ++s4) {
        float4 hv = *(const float4*)(Hp + s4*4);
        h[s4*4+0] = hv.x; h[s4*4+1] = hv.y; h[s4*4+2] = hv.z; h[s4*4+3] = hv.w;
    }
    int l0 = c * CLEN;
    size_t rowbase = (size_t)b * LL + l0;
    const unsigned short* px = xzb + rowbase * 256 + d;
    const unsigned short* pz = xzb + rowbase * 256 + 128 + d;
    unsigned short* pym = ymb + rowbase * 128 + d;
    float w0 = 0.f, w1 = 0.f, w2 = 0.f;
    if (l0) { w0 = b2f(px[-768]); w1 = b2f(px[-512]); w2 = b2f(px[-256]); }
    for (int t = 0; t < CLEN; ++t) {
        float cur = b2f(px[(size_t)t * 256]);
        float sv = cbias + w0*cw.x + w1*cw.y + w2*cw.z + cur*cw.w;
        float xs = sv / (1.f + __expf(-sv));
        w0 = w1; w1 = w2; w2 = cur;
        float4 di = *(const float4*)&sdbl[half][t][0];
        float dtv = di.x*w4.x + di.y*w4.y + di.z*w4.z + di.w*w4.w + dbias;
        dtv = (dtv > 15.f) ? dtv : __logf(1.f + __expf(dtv));
        float dx = dtv * xs;
        float y0 = 0.f, y1 = 0.f;
#pragma unroll
        for (int s = 0; s < 8; ++s) {
            float da = __builtin_amdgcn_exp2f(dtv * Ads2[s]);
            h[s] = da * h[s] + dx * sdbl[half][t][4 + s];
            y0 += h[s] * sdbl[half][t][20 + s];
        }
#pragma unroll
        for (int s = 8; s < 16; ++s) {
            float da = __builtin_amdgcn_exp2f(dtv * Ads2[s]);
            h[s] = da * h[s] + dx * sdbl[half][t][4 + s];
            y1 += h[s] * sdbl[half][t][20 + s];
        }
        float y = y0 + y1 + xs * Dv;
        float zv = b2f(pz[(size_t)t * 256]);
        y *= zv / (1.f + __expf(-zv));
        pym[(size_t)t * 128] = f2b(y);
    }
}

// ---------------------------------------------------------------
// BN apply + residual + transpose -> bf16 (B,L,64).
// ---------------------------------------------------------------
__global__ __launch_bounds__(256) void k_bnapply_t(const float* __restrict__ xm,
        const float* __restrict__ stats, const float* __restrict__ gamma,
        const float* __restrict__ beta, const float* __restrict__ xin,
        unsigned short* __restrict__ xf) {
    __shared__ float t[64][65];
    int tid = threadIdx.x;
    int b = blockIdx.x >> 6;
    int l0 = (blockIdx.x & 63) * 64;
    const float inv = 1.f / (float)(BB * LL);
#pragma unroll
    for (int it = 0; it < 16; ++it) {
        int idx = it * 256 + tid;
        int c = idx >> 6, l = idx & 63;
        float mean = stats[c] * inv;
        float var  = stats[64 + c] * inv - mean * mean;
        float g = gamma[c] * rsqrtf(var + 1e-5f);
        float sh = beta[c] - mean * g;
        size_t addr = ((size_t)b * DD + c) * LL + l0 + l;
        t[c][l] = xm[addr] * g + sh + xin[addr];
    }
    __syncthreads();
#pragma unroll
    for (int it = 0; it < 2; ++it) {
        int idx = it * 256 + tid;
        int l = idx >> 3, c8 = (idx & 7) * 8;
        unsigned short o[8];
#pragma unroll
        for (int j = 0; j < 8; ++j) o[j] = f2b(t[c8 + j][l]);
        *(s8v*)&xf[((size_t)b * LL + l0 + l) * 64 + c8] = *(s8v*)o;
    }
}

// ---------------------------------------------------------------
// PixelShuffle(r=10) + linear upsample + add (xp bf16 in).
// ---------------------------------------------------------------
__global__ __launch_bounds__(256) void k_final(const unsigned short* __restrict__ xp,
        const float* __restrict__ x, float* __restrict__ out) {
    __shared__ float xps[10][257];
    __shared__ float xr[258];
    int tid = threadIdx.x;
    int bid = blockIdx.x;
    int lt = bid & 15;
    int c = (bid >> 4) % 12;
    int b = bid / (16 * 12);
    int l0 = lt * 256;
#pragma unroll
    for (int r = 0; r < 10; ++r)
        xps[r][tid] = b2f(xp[((size_t)b * 120 + r * 12 + c) * LL + l0 + tid]);
    const float* xrow = x + ((size_t)b * 12 + c) * LL;
    for (int i = tid; i < 258; i += 256) {
        int g = l0 - 1 + i;
        g = (g < 0) ? 0 : ((g > LL - 1) ? LL - 1 : g);
        xr[i] = xrow[g];
    }
    __syncthreads();
    size_t obase = ((size_t)b * 12 + c) * OUTL + (size_t)l0 * 10;
#pragma unroll
    for (int u = 0; u < 10; ++u) {
        int j = u * 256 + tid;
        int jg = l0 * 10 + j;
        int l = j / 10, r = j - l * 10;
        float ps = xps[r][l];
        float src = ((float)jg + 0.5f) * 0.1f - 0.5f;
        src = fmaxf(src, 0.f);
        int i0 = (int)src;
        if (i0 > LL - 1) i0 = LL - 1;
        int i1 = (i0 + 1 < LL) ? i0 + 1 : LL - 1;
        float frac = src - (float)i0;
        float up = xr[i0 - l0 + 1] * (1.f - frac) + xr[i1 - l0 + 1] * frac;
        out[obase + j] = ps + up;
    }
}

// ---------------------------------------------------------------
extern "C" void kernel_launch(void* const* d_in, const int* in_sizes, int n_in,
                              void* d_out, int out_size, void* d_ws, size_t ws_size,
                              hipStream_t stream) {
    const float* x          = (const float*)d_in[0];
    const float* conv_in_w  = (const float*)d_in[1];
    const float* conv_in_b  = (const float*)d_in[2];
    const float* in_proj_w  = (const float*)d_in[3];
    const float* dw_w       = (const float*)d_in[4];
    const float* dw_b       = (const float*)d_in[5];
    const float* x_proj_w   = (const float*)d_in[6];
    const float* dt_w       = (const float*)d_in[7];
    const float* dt_b       = (const float*)d_in[8];
    const float* A_log      = (const float*)d_in[9];
    const float* Dssm       = (const float*)d_in[10];
    const float* out_proj_w = (const float*)d_in[11];
    const float* cm_w       = (const float*)d_in[12];
    const float* cm_b       = (const float*)d_in[13];
    const float* bn_g       = (const float*)d_in[14];
    const float* bn_be      = (const float*)d_in[15];
    const float* ps_w       = (const float*)d_in[16];
    const float* ps_b       = (const float*)d_in[17];

    // Workspace layout (float offsets, NO overlaps; P/Q/Hin = NCH*16384):
    float* ws = (float*)d_ws;
    float* xin_bdl = ws;                                     // [0, 2097152)
    unsigned short* xzb = (unsigned short*)(ws + 2097152);   // [2097152, 6291456)
    float* dbl64   = ws + 6291456;                           // [.., 8388608)
    float* P       = ws + 8388608;                           // [.., 12582912)
    float* Q       = ws + 12582912;                          // [.., 16777216)
    float* Hin     = ws + 16777216;                          // [.., 20971520)
    float* stats   = ws + 20971520;                          // 128
    unsigned short* ymb = (unsigned short*)(ws + 20971648);  // [.., 23068800)
    unsigned short* xmt = (unsigned short*)(ws + 23068800);  // [.., 24117376)
    float* xmerge  = ws + 24117376;                          // [.., 26214528)
    unsigned short* xf  = (unsigned short*)(ws + 26214528);  // [.., 27263104)
    unsigned short* wp_ps = (unsigned short*)(ws + 27263104);
    unsigned short* wp_mg = (unsigned short*)(ws + 27324544);
    unsigned short* xpb = (unsigned short*)(ws + 27355264);  // [.., 29321344)

    k_conv<CIN, 64, 2, true><<<1024, 256, 0, stream>>>(x, conv_in_w, conv_in_b, xin_bdl);
    k_gemm_inproj<<<512, 256, 0, stream>>>(xin_bdl, in_proj_w, xzb);
    k_gemm64dw<36><<<256, 256, 0, stream>>>(xzb, dw_w, dw_b, x_proj_w, dbl64);
    k_scan1<<<1024, 256, 0, stream>>>(xzb, dbl64, dw_w, dw_b, dt_w, dt_b, A_log, P, Q);
    k_scan2<<<64, 256, 0, stream>>>(P, Q, Hin, stats);
    k_scan3<<<1024, 256, 0, stream>>>(xzb, dbl64, dw_w, dw_b, dt_w, dt_b, A_log, Hin,
                                      Dssm, ymb);
    k_wprep<120, 8><<<480, 256, 0, stream>>>(ps_w, wp_ps);
    k_wprep<64, 4><<<240, 256, 0, stream>>>(cm_w, wp_mg);
    k_gemm64_tr<<<256, 256, 0, stream>>>(ymb, out_proj_w, xin_bdl, xmt);
    k_convmfma<64, 4, 0><<<256, 256, 0, stream>>>(xmt, wp_mg, cm_b, xmerge);
    k_bnpart<<<512, 256, 0, stream>>>(xmerge, stats);
    k_bnapply_t<<<512, 256, 0, stream>>>(xmerge, stats, bn_g, bn_be, xin_bdl, xf);
    k_convmfma<120, 8, 1><<<512, 256, 0, stream>>>(xf, wp_ps, ps_b, xpb);
    k_final<<<1536, 256, 0, stream>>>(xpb, x, (float*)d_out);
}